// Round 5
// baseline (1536.913 us; speedup 1.0000x reference)
//
#include <hip/hip_runtime.h>
#include <float.h>

#define F_DIM 256
#define N_DIM 512
#define B_DIM 192
#define K_TOP 10

typedef __attribute__((ext_vector_type(8))) short short8;
typedef __attribute__((ext_vector_type(4))) float f32x4;

__device__ inline unsigned short f2bf(float x) {
    unsigned u = __builtin_bit_cast(unsigned, x);
    return (unsigned short)((u + 0x7fffu + ((u >> 16) & 1u)) >> 16);
}

// ---------------------------------------------------------------------------
// k_combine (grid 514):
//   bx<256 : Wt1[j][f=bx] = bf16( sum_h g_w[h,f]*w1[h,j] )
//   bx==256: bc[j] = sum_h g_b[h]*w1[h,j]
//   bx>256 : W2t[j][f] = bf16(w2[f][j])
// ---------------------------------------------------------------------------
__global__ __launch_bounds__(256) void k_combine(const float* __restrict__ g_w,
                                                 const float* __restrict__ g_b,
                                                 const float* __restrict__ w1,
                                                 const float* __restrict__ w2,
                                                 unsigned short* __restrict__ Wt1,
                                                 float* __restrict__ bc,
                                                 unsigned short* __restrict__ W2t) {
    const int j = threadIdx.x;
    const int bx = blockIdx.x;
    if (bx < F_DIM) {
        float acc = 0.f;
        for (int h = 0; h < F_DIM; ++h) acc += g_w[h * F_DIM + bx] * w1[h * F_DIM + j];
        Wt1[j * F_DIM + bx] = f2bf(acc);
    } else if (bx == F_DIM) {
        float acc = 0.f;
        for (int h = 0; h < F_DIM; ++h) acc += g_b[h] * w1[h * F_DIM + j];
        bc[j] = acc;
    } else {
        int f = bx - F_DIM - 1;
        W2t[j * F_DIM + f] = f2bf(w2[f * F_DIM + j]);
    }
}

// ---------------------------------------------------------------------------
// k_to_bf16t: vt[b][n][f] = bf16(v[b][f][n])
// ---------------------------------------------------------------------------
__global__ __launch_bounds__(256) void k_to_bf16t(const float* __restrict__ v,
                                                  unsigned short* __restrict__ vt) {
    __shared__ float tile[32][33];
    const int b = blockIdx.z;
    const int n0 = blockIdx.x * 32;
    const int f0 = blockIdx.y * 32;
    const int tx = threadIdx.x & 31, ty = threadIdx.x >> 5;
    const float* vb = v + (size_t)b * F_DIM * N_DIM;
#pragma unroll
    for (int q = 0; q < 4; ++q)
        tile[ty + q * 8][tx] = vb[(size_t)(f0 + ty + q * 8) * N_DIM + n0 + tx];
    __syncthreads();
    const int wn = threadIdx.x >> 4;
    const int wf = threadIdx.x & 15;
    unsigned* vt32 = (unsigned*)vt;
#pragma unroll
    for (int q2 = 0; q2 < 2; ++q2) {
        int row = wn + q2 * 16;
        unsigned lo = f2bf(tile[wf * 2][row]);
        unsigned hi = f2bf(tile[wf * 2 + 1][row]);
        vt32[(size_t)(b * N_DIM + n0 + row) * (F_DIM / 2) + (f0 >> 1) + wf] = lo | (hi << 16);
    }
}

// ---------------------------------------------------------------------------
// k_topk_reg: block = 64 rows (4 waves x 16). Register-direct MFMA A = vt vt^T.
// XCD-aware remap keeps each batch's 256 KB panel on one XCD's L2.
// Top-10: pairwise tournament tree (depth-5 chain instead of 31-deep serial
// scan) -- associative lexicographic max, bit-identical to the serial scan.
// ---------------------------------------------------------------------------
__global__ __launch_bounds__(256, 2) void k_topk_reg(const unsigned short* __restrict__ vt,
                                                     float* __restrict__ deg,
                                                     int* __restrict__ idxb,
                                                     float* __restrict__ wb) {
    const int lid = blockIdx.y * 8 + blockIdx.x;   // dispatch order, x-fastest
    const int slot = lid >> 3;                     // 0..191
    const int b = (lid & 7) + 8 * (slot >> 3);     // 24 batches per XCD
    const int nblk = slot & 7;

    const int w = threadIdx.x >> 6;
    const int l = threadIdx.x & 63;
    const int l15 = l & 15;
    const int g = l >> 4;
    const int n0w = nblk * 64 + w * 16;
    const unsigned short* vtb = vt + (size_t)b * N_DIM * F_DIM;

    short8 af[8];
#pragma unroll
    for (int s = 0; s < 8; ++s)
        af[s] = *(const short8*)(vtb + (size_t)(n0w + l15) * F_DIM + s * 32 + g * 8);

    f32x4 acc[32];
#pragma unroll
    for (int mt = 0; mt < 32; ++mt) acc[mt] = (f32x4){0.f, 0.f, 0.f, 0.f};

#pragma unroll
    for (int mt = 0; mt < 32; ++mt) {
        const unsigned short* bp = vtb + (size_t)(mt * 16 + l15) * F_DIM + g * 8;
#pragma unroll
        for (int s = 0; s < 8; ++s) {
            short8 bf = *(const short8*)(bp + s * 32);
            acc[mt] = __builtin_amdgcn_mfma_f32_16x16x32_bf16(af[s], bf, acc[mt], 0, 0, 0);
        }
    }

#pragma unroll
    for (int q = 0; q < 4; ++q) {
        float wv[32];
#pragma unroll
        for (int mt = 0; mt < 32; ++mt) wv[mt] = acc[mt][q];
        const int row = b * N_DIM + n0w + g * 4 + q;
        float sum = 0.f;
        for (int it = 0; it < K_TOP; ++it) {
            // tournament tree over 32 candidates (value, mt), lowest mt on tie
            float tv[32]; int ti[32];
#pragma unroll
            for (int mt = 0; mt < 32; ++mt) { tv[mt] = wv[mt]; ti[mt] = mt; }
#pragma unroll
            for (int len = 16; len >= 1; len >>= 1) {
#pragma unroll
                for (int i = 0; i < 16; ++i) {
                    if (i < len) {
                        bool take = (tv[i + len] > tv[i]) ||
                                    (tv[i + len] == tv[i] && ti[i + len] < ti[i]);
                        tv[i] = take ? tv[i + len] : tv[i];
                        ti[i] = take ? ti[i + len] : ti[i];
                    }
                }
            }
            float bv = tv[0];
            int bi = (ti[0] << 4) | l15;           // global col before x-lane
            // cross-lane reduce within the 16-lane group
#pragma unroll
            for (int off = 1; off <= 8; off <<= 1) {
                float ov = __shfl_xor(bv, off, 64);
                int   oi = __shfl_xor(bi, off, 64);
                if (ov > bv || (ov == bv && oi < bi)) { bv = ov; bi = oi; }
            }
            sum += bv;
            if (it < K_TOP - 1) {                  // knockout (skip on last iter)
                const int kmt = bi >> 4;
                const bool own = (bi & 15) == l15;
#pragma unroll
                for (int mt = 0; mt < 32; ++mt)
                    wv[mt] = (own && kmt == mt) ? -FLT_MAX : wv[mt];
            }
            if (l15 == 0) {
                idxb[row * K_TOP + it] = bi;
                wb[row * (K_TOP + 1) + it] = bv;
            }
        }
        if (l15 == 0) deg[row] = sum + 1.0f;
    }
}

// ---------------------------------------------------------------------------
// k_gemm_mfma: per batch C[512,256] = At(bf16) @ Wt^T(bf16), register-direct
// ---------------------------------------------------------------------------
template <bool ADD_BIAS>
__global__ __launch_bounds__(256, 2) void k_gemm_mfma(const unsigned short* __restrict__ At,
                                                      const unsigned short* __restrict__ Wt,
                                                      const float* __restrict__ bias,
                                                      float* __restrict__ C) {
    const int b = blockIdx.y;
    const int w = threadIdx.x >> 6;
    const int l = threadIdx.x & 63;
    const int l15 = l & 15;
    const int g = l >> 4;
    const int n0w = blockIdx.x * 128 + w * 32;
    const unsigned short* Ab = At + (size_t)b * N_DIM * F_DIM;

    f32x4 acc0[16], acc1[16];
#pragma unroll
    for (int jt = 0; jt < 16; ++jt) {
        acc0[jt] = (f32x4){0.f, 0.f, 0.f, 0.f};
        acc1[jt] = (f32x4){0.f, 0.f, 0.f, 0.f};
    }

    for (int s = 0; s < 8; ++s) {
        short8 a0 = *(const short8*)(Ab + (size_t)(n0w + l15) * F_DIM + s * 32 + g * 8);
        short8 a1 = *(const short8*)(Ab + (size_t)(n0w + 16 + l15) * F_DIM + s * 32 + g * 8);
#pragma unroll
        for (int jt = 0; jt < 16; ++jt) {
            short8 bf = *(const short8*)(Wt + (size_t)(jt * 16 + l15) * F_DIM + s * 32 + g * 8);
            acc0[jt] = __builtin_amdgcn_mfma_f32_16x16x32_bf16(a0, bf, acc0[jt], 0, 0, 0);
            acc1[jt] = __builtin_amdgcn_mfma_f32_16x16x32_bf16(a1, bf, acc1[jt], 0, 0, 0);
        }
    }

#pragma unroll
    for (int jt = 0; jt < 16; ++jt) {
        float bv = ADD_BIAS ? bias[jt * 16 + l15] : 0.f;
#pragma unroll
        for (int q = 0; q < 4; ++q) {
            int r0 = n0w + g * 4 + q;
            C[((size_t)b * N_DIM + r0) * F_DIM + jt * 16 + l15] = acc0[jt][q] + bv;
            int r1 = n0w + 16 + g * 4 + q;
            C[((size_t)b * N_DIM + r1) * F_DIM + jt * 16 + l15] = acc1[jt][q] + bv;
        }
    }
}

// ---------------------------------------------------------------------------
// k_spmm_bf16: x1 = relu(A_hat @ h1 + b1), scale fused. bf16 out. XCD remap.
// ---------------------------------------------------------------------------
__global__ __launch_bounds__(256) void k_spmm_bf16(const float* __restrict__ X,
                                                   const int* __restrict__ idxb,
                                                   const float* __restrict__ wbr,
                                                   const float* __restrict__ deg,
                                                   const float* __restrict__ bias,
                                                   unsigned short* __restrict__ Y) {
    const int lid = blockIdx.x;                 // 24576 blocks
    const int slot = lid >> 3;                  // 0..3071
    const int b = (lid & 7) + 8 * (slot >> 7);  // 24 batches per XCD
    const int rowblk = slot & 127;
    const int w = threadIdx.x >> 6;
    const int l = threadIdx.x & 63;
    const int row = b * N_DIM + rowblk * 4 + w;

    const float* Xb = X + ((size_t)b << 9) * F_DIM;
    const float* degb = deg + b * N_DIM;
    const int* id = idxb + row * K_TOP;
    const float* raw = wbr + row * (K_TOP + 1);

    const float dgs = deg[row];
    const float dn = (dgs == 0.f) ? 0.f : 1.f / sqrtf(dgs);
    float4 bv = ((const float4*)bias)[l];
    float4 xv = ((const float4*)(X + (size_t)row * F_DIM))[l];
    const float ws = dn * dn;
    float4 acc;
    acc.x = ws * xv.x + bv.x; acc.y = ws * xv.y + bv.y;
    acc.z = ws * xv.z + bv.z; acc.w = ws * xv.w + bv.w;
#pragma unroll
    for (int i = 0; i < K_TOP; ++i) {
        int m = id[i];
        float dgm = degb[m];
        float dm = (dgm == 0.f) ? 0.f : 1.f / sqrtf(dgm);
        float wi = dn * raw[i] * dm;
        float4 gv = ((const float4*)(Xb + ((size_t)m << 8)))[l];
        acc.x += wi * gv.x; acc.y += wi * gv.y;
        acc.z += wi * gv.z; acc.w += wi * gv.w;
    }
    acc.x = fmaxf(acc.x, 0.f); acc.y = fmaxf(acc.y, 0.f);
    acc.z = fmaxf(acc.z, 0.f); acc.w = fmaxf(acc.w, 0.f);
    uint2 p;
    p.x = (unsigned)f2bf(acc.x) | ((unsigned)f2bf(acc.y) << 16);
    p.y = (unsigned)f2bf(acc.z) | ((unsigned)f2bf(acc.w) << 16);
    ((uint2*)Y)[(size_t)row * (F_DIM / 4) + l] = p;
}

// ---------------------------------------------------------------------------
// k_spmm_trans: x2 = A_hat @ h2 + b2 (scale fused), then out = x2^T + v
// ---------------------------------------------------------------------------
__global__ __launch_bounds__(256) void k_spmm_trans(const float* __restrict__ X,
                                                    const int* __restrict__ idxb,
                                                    const float* __restrict__ wbr,
                                                    const float* __restrict__ deg,
                                                    const float* __restrict__ bias,
                                                    const float* __restrict__ v,
                                                    float* __restrict__ out) {
    __shared__ float tile[32][257];
    const int lid = blockIdx.x;                 // 3072 blocks
    const int slot = lid >> 3;                  // 0..383
    const int b = (lid & 7) + 8 * (slot >> 4);
    const int n0 = (slot & 15) * 32;
    const int w = threadIdx.x >> 6;
    const int l = threadIdx.x & 63;

    const float* Xb = X + ((size_t)b << 9) * F_DIM;
    const float* degb = deg + b * N_DIM;
    float4 bv = ((const float4*)bias)[l];

    for (int r8 = 0; r8 < 8; ++r8) {
        const int rloc = w * 8 + r8;
        const int row = b * N_DIM + n0 + rloc;
        const int* id = idxb + row * K_TOP;
        const float* raw = wbr + row * (K_TOP + 1);
        const float dgs = deg[row];
        const float dn = (dgs == 0.f) ? 0.f : 1.f / sqrtf(dgs);
        float4 xv = ((const float4*)(X + (size_t)row * F_DIM))[l];
        const float ws = dn * dn;
        float4 acc;
        acc.x = ws * xv.x + bv.x; acc.y = ws * xv.y + bv.y;
        acc.z = ws * xv.z + bv.z; acc.w = ws * xv.w + bv.w;
#pragma unroll
        for (int i = 0; i < K_TOP; ++i) {
            int m = id[i];
            float dgm = degb[m];
            float dm = (dgm == 0.f) ? 0.f : 1.f / sqrtf(dgm);
            float wi = dn * raw[i] * dm;
            float4 gv = ((const float4*)(Xb + ((size_t)m << 8)))[l];
            acc.x += wi * gv.x; acc.y += wi * gv.y;
            acc.z += wi * gv.z; acc.w += wi * gv.w;
        }
        tile[rloc][l * 4 + 0] = acc.x;
        tile[rloc][l * 4 + 1] = acc.y;
        tile[rloc][l * 4 + 2] = acc.z;
        tile[rloc][l * 4 + 3] = acc.w;
    }
    __syncthreads();

    const int i8 = l & 7;
    const int j8 = l >> 3;
#pragma unroll
    for (int k = 0; k < 8; ++k) {
        const int f = (k * 4 + w) * 8 + j8;
        const size_t vo = (size_t)b * F_DIM * N_DIM + (size_t)f * N_DIM + n0;
        float4 vv = ((const float4*)(v + vo))[i8];
        float4 o;
        o.x = tile[i8 * 4 + 0][f] + vv.x;
        o.y = tile[i8 * 4 + 1][f] + vv.y;
        o.z = tile[i8 * 4 + 2][f] + vv.z;
        o.w = tile[i8 * 4 + 3][f] + vv.w;
        ((float4*)(out + vo))[i8] = o;
    }
}

// ---------------------------------------------------------------------------
extern "C" void kernel_launch(void* const* d_in, const int* in_sizes, int n_in,
                              void* d_out, int out_size, void* d_ws, size_t ws_size,
                              hipStream_t stream) {
    const float* v   = (const float*)d_in[0];
    const float* g_w = (const float*)d_in[1];
    const float* g_b = (const float*)d_in[2];
    const float* w1  = (const float*)d_in[3];
    const float* b1  = (const float*)d_in[4];
    const float* w2  = (const float*)d_in[5];
    const float* b2  = (const float*)d_in[6];
    float* out = (float*)d_out;

    const size_t S = (size_t)B_DIM * N_DIM * F_DIM;
    float* bufA = (float*)d_ws;                     // h1, then h2 (fp32)
    float* bufB = bufA + S;                         // vt(bf16) -> x1bf(bf16)
    float* bc   = bufB + S;
    float* deg  = bc + F_DIM;
    float* wb   = deg + (size_t)B_DIM * N_DIM;      // raw top-10 values
    int*   idxb = (int*)(wb + (size_t)B_DIM * N_DIM * (K_TOP + 1));
    unsigned short* Wt1 = (unsigned short*)(idxb + (size_t)B_DIM * N_DIM * K_TOP);
    unsigned short* W2t = Wt1 + F_DIM * F_DIM;

    unsigned short* vt   = (unsigned short*)bufB;
    unsigned short* x1bf = (unsigned short*)bufB;   // overwrites vt (dead after gemm1)

    k_combine<<<dim3(2 * F_DIM + 2), 256, 0, stream>>>(g_w, g_b, w1, w2, Wt1, bc, W2t);
    k_to_bf16t<<<dim3(N_DIM / 32, F_DIM / 32, B_DIM), 256, 0, stream>>>(v, vt);
    k_topk_reg<<<dim3(N_DIM / 64, B_DIM), 256, 0, stream>>>(vt, deg, idxb, wb);
    // h1 = vt @ Wt1^T + bc -> bufA
    k_gemm_mfma<true><<<dim3(N_DIM / 128, B_DIM), 256, 0, stream>>>(vt, Wt1, bc, bufA);
    // x1 = relu(A_hat @ h1 + b1) -> x1bf (bf16), scale fused
    k_spmm_bf16<<<dim3(B_DIM * N_DIM / 4), 256, 0, stream>>>(bufA, idxb, wb, deg, b1, x1bf);
    // h2 = x1bf @ W2t^T -> bufA
    k_gemm_mfma<false><<<dim3(N_DIM / 128, B_DIM), 256, 0, stream>>>(x1bf, W2t, nullptr, bufA);
    // out = (A_hat @ h2 + b2)^T + v, scale+transpose+residual fused
    k_spmm_trans<<<dim3(B_DIM * N_DIM / 32), 256, 0, stream>>>(bufA, idxb, wb, deg, b2, v, out);
}

// Round 6
// 678.080 us; speedup vs baseline: 2.2666x; 2.2666x over previous
//
#include <hip/hip_runtime.h>
#include <float.h>

#define F_DIM 256
#define N_DIM 512
#define B_DIM 192
#define K_TOP 10

typedef __attribute__((ext_vector_type(8))) short short8;
typedef __attribute__((ext_vector_type(4))) float f32x4;

__device__ inline unsigned short f2bf(float x) {
    unsigned u = __builtin_bit_cast(unsigned, x);
    return (unsigned short)((u + 0x7fffu + ((u >> 16) & 1u)) >> 16);
}

// ---------------------------------------------------------------------------
// k_combine (grid 514):
//   bx<256 : Wt1[j][f=bx] = bf16( sum_h g_w[h,f]*w1[h,j] )
//   bx==256: bc[j] = sum_h g_b[h]*w1[h,j]
//   bx>256 : W2t[j][f] = bf16(w2[f][j])
// ---------------------------------------------------------------------------
__global__ __launch_bounds__(256) void k_combine(const float* __restrict__ g_w,
                                                 const float* __restrict__ g_b,
                                                 const float* __restrict__ w1,
                                                 const float* __restrict__ w2,
                                                 unsigned short* __restrict__ Wt1,
                                                 float* __restrict__ bc,
                                                 unsigned short* __restrict__ W2t) {
    const int j = threadIdx.x;
    const int bx = blockIdx.x;
    if (bx < F_DIM) {
        float acc = 0.f;
        for (int h = 0; h < F_DIM; ++h) acc += g_w[h * F_DIM + bx] * w1[h * F_DIM + j];
        Wt1[j * F_DIM + bx] = f2bf(acc);
    } else if (bx == F_DIM) {
        float acc = 0.f;
        for (int h = 0; h < F_DIM; ++h) acc += g_b[h] * w1[h * F_DIM + j];
        bc[j] = acc;
    } else {
        int f = bx - F_DIM - 1;
        W2t[j * F_DIM + f] = f2bf(w2[f * F_DIM + j]);
    }
}

// ---------------------------------------------------------------------------
// k_to_bf16t: vt[b][n][f] = bf16(v[b][f][n])
// ---------------------------------------------------------------------------
__global__ __launch_bounds__(256) void k_to_bf16t(const float* __restrict__ v,
                                                  unsigned short* __restrict__ vt) {
    __shared__ float tile[32][33];
    const int b = blockIdx.z;
    const int n0 = blockIdx.x * 32;
    const int f0 = blockIdx.y * 32;
    const int tx = threadIdx.x & 31, ty = threadIdx.x >> 5;
    const float* vb = v + (size_t)b * F_DIM * N_DIM;
#pragma unroll
    for (int q = 0; q < 4; ++q)
        tile[ty + q * 8][tx] = vb[(size_t)(f0 + ty + q * 8) * N_DIM + n0 + tx];
    __syncthreads();
    const int wn = threadIdx.x >> 4;
    const int wf = threadIdx.x & 15;
    unsigned* vt32 = (unsigned*)vt;
#pragma unroll
    for (int q2 = 0; q2 < 2; ++q2) {
        int row = wn + q2 * 16;
        unsigned lo = f2bf(tile[wf * 2][row]);
        unsigned hi = f2bf(tile[wf * 2 + 1][row]);
        vt32[(size_t)(b * N_DIM + n0 + row) * (F_DIM / 2) + (f0 >> 1) + wf] = lo | (hi << 16);
    }
}

// ---------------------------------------------------------------------------
// k_topk_reg: block = 64 rows (4 waves x 16). Register-direct MFMA computes the
// TRANSPOSED tile (operands swapped): D[r=m][c=n] -> lane owns ONE row
// n = n0w + (l&15), holding 128 column-values in acc (cols m = mt*16+g*4+q).
// Selection: 10 iterations total for all 16 rows; per-lane chunked tournament
// (4x32, temps <=32 regs -- no spills), 2-shfl cross-group reduce, static
// 128-way knockout. Bit-identical to R4 selection semantics.
// ---------------------------------------------------------------------------
__global__ __launch_bounds__(256, 2) void k_topk_reg(const unsigned short* __restrict__ vt,
                                                     float* __restrict__ deg,
                                                     int* __restrict__ idxb,
                                                     float* __restrict__ wb) {
    const int lid = blockIdx.y * 8 + blockIdx.x;   // dispatch order, x-fastest
    const int slot = lid >> 3;                     // 0..191
    const int b = (lid & 7) + 8 * (slot >> 3);     // 24 batches per XCD
    const int nblk = slot & 7;

    const int w = threadIdx.x >> 6;
    const int l = threadIdx.x & 63;
    const int l15 = l & 15;
    const int g = l >> 4;
    const int n0w = nblk * 64 + w * 16;
    const unsigned short* vtb = vt + (size_t)b * N_DIM * F_DIM;

    // B-operand fragments: our 16 rows (col dim of D)
    short8 bf[8];
#pragma unroll
    for (int s = 0; s < 8; ++s)
        bf[s] = *(const short8*)(vtb + (size_t)(n0w + l15) * F_DIM + s * 32 + g * 8);

    f32x4 acc[32];
#pragma unroll
    for (int mt = 0; mt < 32; ++mt) acc[mt] = (f32x4){0.f, 0.f, 0.f, 0.f};

    // A-operand: the 512 scan columns (row dim of D). Swapped vs R4.
#pragma unroll
    for (int mt = 0; mt < 32; ++mt) {
        const unsigned short* ap = vtb + (size_t)(mt * 16 + l15) * F_DIM + g * 8;
#pragma unroll
        for (int s = 0; s < 8; ++s) {
            short8 a = *(const short8*)(ap + s * 32);
            acc[mt] = __builtin_amdgcn_mfma_f32_16x16x32_bf16(a, bf[s], acc[mt], 0, 0, 0);
        }
    }

    // ---- selection: lane owns row n0w+l15; its 128 values: e=(mt<<2)|q,
    //      col m = (e>>2)*16 + g*4 + (e&3) ----
    const int row = b * N_DIM + n0w + l15;
    float sum = 0.f;
    for (int it = 0; it < K_TOP; ++it) {
        float chv[4]; int che[4];
#pragma unroll
        for (int c = 0; c < 4; ++c) {
            float tv[16]; int te[16];
#pragma unroll
            for (int p = 0; p < 16; ++p) {
                const int e0 = c * 32 + 2 * p, e1 = e0 + 1;
                float a = acc[e0 >> 2][e0 & 3];
                float bb2 = acc[e1 >> 2][e1 & 3];
                bool tk = bb2 > a;                 // keep lower e on tie
                tv[p] = tk ? bb2 : a;
                te[p] = tk ? e1 : e0;
            }
#pragma unroll
            for (int len = 8; len >= 1; len >>= 1) {
#pragma unroll
                for (int i2 = 0; i2 < 8; ++i2) {
                    if (i2 < len) {
                        bool tk = tv[i2 + len] > tv[i2];
                        tv[i2] = tk ? tv[i2 + len] : tv[i2];
                        te[i2] = tk ? te[i2 + len] : te[i2];
                    }
                }
            }
            chv[c] = tv[0]; che[c] = te[0];
        }
        bool t1 = chv[1] > chv[0];
        float m0 = t1 ? chv[1] : chv[0]; int ea = t1 ? che[1] : che[0];
        bool t2 = chv[3] > chv[2];
        float m1 = t2 ? chv[3] : chv[2]; int eb = t2 ? che[3] : che[2];
        bool t3 = m1 > m0;
        float bv = t3 ? m1 : m0; int be = t3 ? eb : ea;
        int bm = ((be >> 2) << 4) | (g << 2) | (be & 3);   // global col m

        // cross-group reduce: lanes {l15, l15+16, l15+32, l15+48}
#pragma unroll
        for (int off = 16; off <= 32; off <<= 1) {
            float ov = __shfl_xor(bv, off, 64);
            int om = __shfl_xor(bm, off, 64);
            if (ov > bv || (ov == bv && om < bm)) { bv = ov; bm = om; }
        }
        sum += bv;
        if (l < 16) {
            idxb[row * K_TOP + it] = bm;
            wb[row * (K_TOP + 1) + it] = bv;
        }
        if (it < K_TOP - 1) {
            int eo = ((bm >> 4) << 2) | (bm & 3);
            eo = (((bm >> 2) & 3) == g) ? eo : 999;        // only owner knocks out
#pragma unroll
            for (int e = 0; e < 128; ++e)
                acc[e >> 2][e & 3] = (e == eo) ? -FLT_MAX : acc[e >> 2][e & 3];
        }
    }
    if (l < 16) deg[row] = sum + 1.0f;
}

// ---------------------------------------------------------------------------
// k_gemm_mfma: per batch C[512,256] = At(bf16) @ Wt^T(bf16), register-direct
// ---------------------------------------------------------------------------
template <bool ADD_BIAS>
__global__ __launch_bounds__(256, 2) void k_gemm_mfma(const unsigned short* __restrict__ At,
                                                      const unsigned short* __restrict__ Wt,
                                                      const float* __restrict__ bias,
                                                      float* __restrict__ C) {
    const int b = blockIdx.y;
    const int w = threadIdx.x >> 6;
    const int l = threadIdx.x & 63;
    const int l15 = l & 15;
    const int g = l >> 4;
    const int n0w = blockIdx.x * 128 + w * 32;
    const unsigned short* Ab = At + (size_t)b * N_DIM * F_DIM;

    f32x4 acc0[16], acc1[16];
#pragma unroll
    for (int jt = 0; jt < 16; ++jt) {
        acc0[jt] = (f32x4){0.f, 0.f, 0.f, 0.f};
        acc1[jt] = (f32x4){0.f, 0.f, 0.f, 0.f};
    }

    for (int s = 0; s < 8; ++s) {
        short8 a0 = *(const short8*)(Ab + (size_t)(n0w + l15) * F_DIM + s * 32 + g * 8);
        short8 a1 = *(const short8*)(Ab + (size_t)(n0w + 16 + l15) * F_DIM + s * 32 + g * 8);
#pragma unroll
        for (int jt = 0; jt < 16; ++jt) {
            short8 bf = *(const short8*)(Wt + (size_t)(jt * 16 + l15) * F_DIM + s * 32 + g * 8);
            acc0[jt] = __builtin_amdgcn_mfma_f32_16x16x32_bf16(a0, bf, acc0[jt], 0, 0, 0);
            acc1[jt] = __builtin_amdgcn_mfma_f32_16x16x32_bf16(a1, bf, acc1[jt], 0, 0, 0);
        }
    }

#pragma unroll
    for (int jt = 0; jt < 16; ++jt) {
        float bv = ADD_BIAS ? bias[jt * 16 + l15] : 0.f;
#pragma unroll
        for (int q = 0; q < 4; ++q) {
            int r0 = n0w + g * 4 + q;
            C[((size_t)b * N_DIM + r0) * F_DIM + jt * 16 + l15] = acc0[jt][q] + bv;
            int r1 = n0w + 16 + g * 4 + q;
            C[((size_t)b * N_DIM + r1) * F_DIM + jt * 16 + l15] = acc1[jt][q] + bv;
        }
    }
}

// ---------------------------------------------------------------------------
// k_spmm_bf16: x1 = relu(A_hat @ h1 + b1), scale fused. bf16 out. XCD remap.
// ---------------------------------------------------------------------------
__global__ __launch_bounds__(256) void k_spmm_bf16(const float* __restrict__ X,
                                                   const int* __restrict__ idxb,
                                                   const float* __restrict__ wbr,
                                                   const float* __restrict__ deg,
                                                   const float* __restrict__ bias,
                                                   unsigned short* __restrict__ Y) {
    const int lid = blockIdx.x;                 // 24576 blocks
    const int slot = lid >> 3;                  // 0..3071
    const int b = (lid & 7) + 8 * (slot >> 7);  // 24 batches per XCD
    const int rowblk = slot & 127;
    const int w = threadIdx.x >> 6;
    const int l = threadIdx.x & 63;
    const int row = b * N_DIM + rowblk * 4 + w;

    const float* Xb = X + ((size_t)b << 9) * F_DIM;
    const float* degb = deg + b * N_DIM;
    const int* id = idxb + row * K_TOP;
    const float* raw = wbr + row * (K_TOP + 1);

    const float dgs = deg[row];
    const float dn = (dgs == 0.f) ? 0.f : 1.f / sqrtf(dgs);
    float4 bv = ((const float4*)bias)[l];
    float4 xv = ((const float4*)(X + (size_t)row * F_DIM))[l];
    const float ws = dn * dn;
    float4 acc;
    acc.x = ws * xv.x + bv.x; acc.y = ws * xv.y + bv.y;
    acc.z = ws * xv.z + bv.z; acc.w = ws * xv.w + bv.w;
#pragma unroll
    for (int i = 0; i < K_TOP; ++i) {
        int m = id[i];
        float dgm = degb[m];
        float dm = (dgm == 0.f) ? 0.f : 1.f / sqrtf(dgm);
        float wi = dn * raw[i] * dm;
        float4 gv = ((const float4*)(Xb + ((size_t)m << 8)))[l];
        acc.x += wi * gv.x; acc.y += wi * gv.y;
        acc.z += wi * gv.z; acc.w += wi * gv.w;
    }
    acc.x = fmaxf(acc.x, 0.f); acc.y = fmaxf(acc.y, 0.f);
    acc.z = fmaxf(acc.z, 0.f); acc.w = fmaxf(acc.w, 0.f);
    uint2 p;
    p.x = (unsigned)f2bf(acc.x) | ((unsigned)f2bf(acc.y) << 16);
    p.y = (unsigned)f2bf(acc.z) | ((unsigned)f2bf(acc.w) << 16);
    ((uint2*)Y)[(size_t)row * (F_DIM / 4) + l] = p;
}

// ---------------------------------------------------------------------------
// k_spmm_trans: x2 = A_hat @ h2 + b2 (scale fused), then out = x2^T + v
// ---------------------------------------------------------------------------
__global__ __launch_bounds__(256) void k_spmm_trans(const float* __restrict__ X,
                                                    const int* __restrict__ idxb,
                                                    const float* __restrict__ wbr,
                                                    const float* __restrict__ deg,
                                                    const float* __restrict__ bias,
                                                    const float* __restrict__ v,
                                                    float* __restrict__ out) {
    __shared__ float tile[32][257];
    const int lid = blockIdx.x;                 // 3072 blocks
    const int slot = lid >> 3;                  // 0..383
    const int b = (lid & 7) + 8 * (slot >> 4);
    const int n0 = (slot & 15) * 32;
    const int w = threadIdx.x >> 6;
    const int l = threadIdx.x & 63;

    const float* Xb = X + ((size_t)b << 9) * F_DIM;
    const float* degb = deg + b * N_DIM;
    float4 bv = ((const float4*)bias)[l];

    for (int r8 = 0; r8 < 8; ++r8) {
        const int rloc = w * 8 + r8;
        const int row = b * N_DIM + n0 + rloc;
        const int* id = idxb + row * K_TOP;
        const float* raw = wbr + row * (K_TOP + 1);
        const float dgs = deg[row];
        const float dn = (dgs == 0.f) ? 0.f : 1.f / sqrtf(dgs);
        float4 xv = ((const float4*)(X + (size_t)row * F_DIM))[l];
        const float ws = dn * dn;
        float4 acc;
        acc.x = ws * xv.x + bv.x; acc.y = ws * xv.y + bv.y;
        acc.z = ws * xv.z + bv.z; acc.w = ws * xv.w + bv.w;
#pragma unroll
        for (int i = 0; i < K_TOP; ++i) {
            int m = id[i];
            float dgm = degb[m];
            float dm = (dgm == 0.f) ? 0.f : 1.f / sqrtf(dgm);
            float wi = dn * raw[i] * dm;
            float4 gv = ((const float4*)(Xb + ((size_t)m << 8)))[l];
            acc.x += wi * gv.x; acc.y += wi * gv.y;
            acc.z += wi * gv.z; acc.w += wi * gv.w;
        }
        tile[rloc][l * 4 + 0] = acc.x;
        tile[rloc][l * 4 + 1] = acc.y;
        tile[rloc][l * 4 + 2] = acc.z;
        tile[rloc][l * 4 + 3] = acc.w;
    }
    __syncthreads();

    const int i8 = l & 7;
    const int j8 = l >> 3;
#pragma unroll
    for (int k = 0; k < 8; ++k) {
        const int f = (k * 4 + w) * 8 + j8;
        const size_t vo = (size_t)b * F_DIM * N_DIM + (size_t)f * N_DIM + n0;
        float4 vv = ((const float4*)(v + vo))[i8];
        float4 o;
        o.x = tile[i8 * 4 + 0][f] + vv.x;
        o.y = tile[i8 * 4 + 1][f] + vv.y;
        o.z = tile[i8 * 4 + 2][f] + vv.z;
        o.w = tile[i8 * 4 + 3][f] + vv.w;
        ((float4*)(out + vo))[i8] = o;
    }
}

// ---------------------------------------------------------------------------
extern "C" void kernel_launch(void* const* d_in, const int* in_sizes, int n_in,
                              void* d_out, int out_size, void* d_ws, size_t ws_size,
                              hipStream_t stream) {
    const float* v   = (const float*)d_in[0];
    const float* g_w = (const float*)d_in[1];
    const float* g_b = (const float*)d_in[2];
    const float* w1  = (const float*)d_in[3];
    const float* b1  = (const float*)d_in[4];
    const float* w2  = (const float*)d_in[5];
    const float* b2  = (const float*)d_in[6];
    float* out = (float*)d_out;

    const size_t S = (size_t)B_DIM * N_DIM * F_DIM;
    float* bufA = (float*)d_ws;                     // h1, then h2 (fp32)
    float* bufB = bufA + S;                         // vt(bf16) -> x1bf(bf16)
    float* bc   = bufB + S;
    float* deg  = bc + F_DIM;
    float* wb   = deg + (size_t)B_DIM * N_DIM;      // raw top-10 values
    int*   idxb = (int*)(wb + (size_t)B_DIM * N_DIM * (K_TOP + 1));
    unsigned short* Wt1 = (unsigned short*)(idxb + (size_t)B_DIM * N_DIM * K_TOP);
    unsigned short* W2t = Wt1 + F_DIM * F_DIM;

    unsigned short* vt   = (unsigned short*)bufB;
    unsigned short* x1bf = (unsigned short*)bufB;   // overwrites vt (dead after gemm1)

    k_combine<<<dim3(2 * F_DIM + 2), 256, 0, stream>>>(g_w, g_b, w1, w2, Wt1, bc, W2t);
    k_to_bf16t<<<dim3(N_DIM / 32, F_DIM / 32, B_DIM), 256, 0, stream>>>(v, vt);
    k_topk_reg<<<dim3(N_DIM / 64, B_DIM), 256, 0, stream>>>(vt, deg, idxb, wb);
    // h1 = vt @ Wt1^T + bc -> bufA
    k_gemm_mfma<true><<<dim3(N_DIM / 128, B_DIM), 256, 0, stream>>>(vt, Wt1, bc, bufA);
    // x1 = relu(A_hat @ h1 + b1) -> x1bf (bf16), scale fused
    k_spmm_bf16<<<dim3(B_DIM * N_DIM / 4), 256, 0, stream>>>(bufA, idxb, wb, deg, b1, x1bf);
    // h2 = x1bf @ W2t^T -> bufA
    k_gemm_mfma<false><<<dim3(N_DIM / 128, B_DIM), 256, 0, stream>>>(x1bf, W2t, nullptr, bufA);
    // out = (A_hat @ h2 + b2)^T + v, scale+transpose+residual fused
    k_spmm_trans<<<dim3(B_DIM * N_DIM / 32), 256, 0, stream>>>(bufA, idxb, wb, deg, b2, v, out);
}

// Round 7
// 546.084 us; speedup vs baseline: 2.8144x; 1.2417x over previous
//
#include <hip/hip_runtime.h>
#include <float.h>

#define F_DIM 256
#define N_DIM 512
#define B_DIM 192
#define K_TOP 10

typedef __attribute__((ext_vector_type(8))) short short8;
typedef __attribute__((ext_vector_type(4))) float f32x4;

__device__ inline unsigned short f2bf(float x) {
    unsigned u = __builtin_bit_cast(unsigned, x);
    return (unsigned short)((u + 0x7fffu + ((u >> 16) & 1u)) >> 16);
}

// ---------------------------------------------------------------------------
// k_combine (grid 514):
//   bx<256 : Wt1[j][f=bx] = bf16( sum_h g_w[h,f]*w1[h,j] )
//   bx==256: bc[j] = sum_h g_b[h]*w1[h,j]
//   bx>256 : W2t[j][f] = bf16(w2[f][j])
// ---------------------------------------------------------------------------
__global__ __launch_bounds__(256) void k_combine(const float* __restrict__ g_w,
                                                 const float* __restrict__ g_b,
                                                 const float* __restrict__ w1,
                                                 const float* __restrict__ w2,
                                                 unsigned short* __restrict__ Wt1,
                                                 float* __restrict__ bc,
                                                 unsigned short* __restrict__ W2t) {
    const int j = threadIdx.x;
    const int bx = blockIdx.x;
    if (bx < F_DIM) {
        float acc = 0.f;
        for (int h = 0; h < F_DIM; ++h) acc += g_w[h * F_DIM + bx] * w1[h * F_DIM + j];
        Wt1[j * F_DIM + bx] = f2bf(acc);
    } else if (bx == F_DIM) {
        float acc = 0.f;
        for (int h = 0; h < F_DIM; ++h) acc += g_b[h] * w1[h * F_DIM + j];
        bc[j] = acc;
    } else {
        int f = bx - F_DIM - 1;
        W2t[j * F_DIM + f] = f2bf(w2[f * F_DIM + j]);
    }
}

// ---------------------------------------------------------------------------
// k_to_bf16t: vt[b][n][f] = bf16(v[b][f][n])
// ---------------------------------------------------------------------------
__global__ __launch_bounds__(256) void k_to_bf16t(const float* __restrict__ v,
                                                  unsigned short* __restrict__ vt) {
    __shared__ float tile[32][33];
    const int b = blockIdx.z;
    const int n0 = blockIdx.x * 32;
    const int f0 = blockIdx.y * 32;
    const int tx = threadIdx.x & 31, ty = threadIdx.x >> 5;
    const float* vb = v + (size_t)b * F_DIM * N_DIM;
#pragma unroll
    for (int q = 0; q < 4; ++q)
        tile[ty + q * 8][tx] = vb[(size_t)(f0 + ty + q * 8) * N_DIM + n0 + tx];
    __syncthreads();
    const int wn = threadIdx.x >> 4;
    const int wf = threadIdx.x & 15;
    unsigned* vt32 = (unsigned*)vt;
#pragma unroll
    for (int q2 = 0; q2 < 2; ++q2) {
        int row = wn + q2 * 16;
        unsigned lo = f2bf(tile[wf * 2][row]);
        unsigned hi = f2bf(tile[wf * 2 + 1][row]);
        vt32[(size_t)(b * N_DIM + n0 + row) * (F_DIM / 2) + (f0 >> 1) + wf] = lo | (hi << 16);
    }
}

// ---------------------------------------------------------------------------
// k_topk_reg: block = 64 rows (4 waves x 16). A = vt vt^T (transposed-operand
// MFMA: lane owns ONE output row). Panel staged through LDS ONCE per block
// (double-buffered global_load_lds, 8 chunks of 512x32 bf16), replacing the
// per-wave L1-thrashing register-direct loads. XOR-swizzled 16B slots
// (involution: pre-swizzled source + swizzled ds_read). Selection identical
// to R6 (bit-identical results).
// ---------------------------------------------------------------------------
__global__ __launch_bounds__(256, 2) void k_topk_reg(const unsigned short* __restrict__ vt,
                                                     float* __restrict__ deg,
                                                     int* __restrict__ idxb,
                                                     float* __restrict__ wb) {
    __shared__ unsigned short stage[2][N_DIM * 32];   // 2 x 32 KB

    const int lid = blockIdx.y * 8 + blockIdx.x;   // dispatch order, x-fastest
    const int slot = lid >> 3;                     // 0..191
    const int b = (lid & 7) + 8 * (slot >> 3);     // 24 batches per XCD
    const int nblk = slot & 7;

    const int w = threadIdx.x >> 6;
    const int l = threadIdx.x & 63;
    const int l15 = l & 15;
    const int g = l >> 4;
    const int n0w = nblk * 64 + w * 16;
    const unsigned short* vtb = vt + (size_t)b * N_DIM * F_DIM;

    // B-operand fragments: our 16 rows (col dim of D), register-resident
    short8 bf[8];
#pragma unroll
    for (int s = 0; s < 8; ++s)
        bf[s] = *(const short8*)(vtb + (size_t)(n0w + l15) * F_DIM + s * 32 + g * 8);

    f32x4 acc[32];
#pragma unroll
    for (int mt = 0; mt < 32; ++mt) acc[mt] = (f32x4){0.f, 0.f, 0.f, 0.f};

    // stage chunk c (512 rows x 32 f) into buf: linear LDS dest, inverse-
    // swizzled global source (slot sl of row -> f-offset sl ^ ((row>>1)&3))
#define STAGE(c, bufi)                                                           \
    {                                                                            \
        _Pragma("unroll")                                                        \
        for (int k = 0; k < 8; ++k) {                                            \
            int sid = w * 512 + k * 64 + l;                                      \
            int row = sid >> 2;                                                  \
            int sl = sid & 3;                                                    \
            const unsigned short* src = vtb + (size_t)row * F_DIM + (c) * 32 +   \
                                        ((sl ^ ((row >> 1) & 3)) << 3);          \
            __builtin_amdgcn_global_load_lds(                                    \
                (const __attribute__((address_space(1))) void*)src,              \
                (__attribute__((address_space(3))) void*)(                       \
                    (char*)&stage[bufi][0] + (size_t)(w * 512 + k * 64) * 16),   \
                16, 0, 0);                                                       \
        }                                                                        \
    }

    STAGE(0, 0);
    asm volatile("s_waitcnt vmcnt(0)" ::: "memory");
    __syncthreads();

    const int slx = g ^ ((l15 >> 1) & 3);   // swizzled 16B slot for our g
    for (int c = 0; c < 8; ++c) {
        const int cur = c & 1;
        if (c < 7) STAGE(c + 1, cur ^ 1);
        const char* sb = (const char*)&stage[cur][0];
        short8 bcur = bf[c];
#pragma unroll
        for (int mt = 0; mt < 32; ++mt) {
            const int row = mt * 16 + l15;
            short8 a = *(const short8*)(sb + row * 64 + (slx << 4));
            acc[mt] = __builtin_amdgcn_mfma_f32_16x16x32_bf16(a, bcur, acc[mt], 0, 0, 0);
        }
        asm volatile("s_waitcnt vmcnt(0)" ::: "memory");
        __syncthreads();
    }
#undef STAGE

    // ---- selection: lane owns row n0w+l15; its 128 values: e=(mt<<2)|q,
    //      col m = (e>>2)*16 + g*4 + (e&3) ----
    const int row = b * N_DIM + n0w + l15;
    float sum = 0.f;
    for (int it = 0; it < K_TOP; ++it) {
        float chv[4]; int che[4];
#pragma unroll
        for (int c = 0; c < 4; ++c) {
            float tv[16]; int te[16];
#pragma unroll
            for (int p = 0; p < 16; ++p) {
                const int e0 = c * 32 + 2 * p, e1 = e0 + 1;
                float a = acc[e0 >> 2][e0 & 3];
                float bb2 = acc[e1 >> 2][e1 & 3];
                bool tk = bb2 > a;                 // keep lower e on tie
                tv[p] = tk ? bb2 : a;
                te[p] = tk ? e1 : e0;
            }
#pragma unroll
            for (int len = 8; len >= 1; len >>= 1) {
#pragma unroll
                for (int i2 = 0; i2 < 8; ++i2) {
                    if (i2 < len) {
                        bool tk = tv[i2 + len] > tv[i2];
                        tv[i2] = tk ? tv[i2 + len] : tv[i2];
                        te[i2] = tk ? te[i2 + len] : te[i2];
                    }
                }
            }
            chv[c] = tv[0]; che[c] = te[0];
        }
        bool t1 = chv[1] > chv[0];
        float m0 = t1 ? chv[1] : chv[0]; int ea = t1 ? che[1] : che[0];
        bool t2 = chv[3] > chv[2];
        float m1 = t2 ? chv[3] : chv[2]; int eb = t2 ? che[3] : che[2];
        bool t3 = m1 > m0;
        float bv = t3 ? m1 : m0; int be = t3 ? eb : ea;
        int bm = ((be >> 2) << 4) | (g << 2) | (be & 3);   // global col m

        // cross-group reduce: lanes {l15, l15+16, l15+32, l15+48}
#pragma unroll
        for (int off = 16; off <= 32; off <<= 1) {
            float ov = __shfl_xor(bv, off, 64);
            int om = __shfl_xor(bm, off, 64);
            if (ov > bv || (ov == bv && om < bm)) { bv = ov; bm = om; }
        }
        sum += bv;
        if (l < 16) {
            idxb[row * K_TOP + it] = bm;
            wb[row * (K_TOP + 1) + it] = bv;
        }
        if (it < K_TOP - 1) {
            int eo = ((bm >> 4) << 2) | (bm & 3);
            eo = (((bm >> 2) & 3) == g) ? eo : 999;        // only owner knocks out
#pragma unroll
            for (int e = 0; e < 128; ++e)
                acc[e >> 2][e & 3] = (e == eo) ? -FLT_MAX : acc[e >> 2][e & 3];
        }
    }
    if (l < 16) deg[row] = sum + 1.0f;
}

// ---------------------------------------------------------------------------
// k_gemm_mfma: per batch C[512,256] = At(bf16) @ Wt^T(bf16), register-direct
// ---------------------------------------------------------------------------
template <bool ADD_BIAS>
__global__ __launch_bounds__(256, 2) void k_gemm_mfma(const unsigned short* __restrict__ At,
                                                      const unsigned short* __restrict__ Wt,
                                                      const float* __restrict__ bias,
                                                      float* __restrict__ C) {
    const int b = blockIdx.y;
    const int w = threadIdx.x >> 6;
    const int l = threadIdx.x & 63;
    const int l15 = l & 15;
    const int g = l >> 4;
    const int n0w = blockIdx.x * 128 + w * 32;
    const unsigned short* Ab = At + (size_t)b * N_DIM * F_DIM;

    f32x4 acc0[16], acc1[16];
#pragma unroll
    for (int jt = 0; jt < 16; ++jt) {
        acc0[jt] = (f32x4){0.f, 0.f, 0.f, 0.f};
        acc1[jt] = (f32x4){0.f, 0.f, 0.f, 0.f};
    }

    for (int s = 0; s < 8; ++s) {
        short8 a0 = *(const short8*)(Ab + (size_t)(n0w + l15) * F_DIM + s * 32 + g * 8);
        short8 a1 = *(const short8*)(Ab + (size_t)(n0w + 16 + l15) * F_DIM + s * 32 + g * 8);
#pragma unroll
        for (int jt = 0; jt < 16; ++jt) {
            short8 bf = *(const short8*)(Wt + (size_t)(jt * 16 + l15) * F_DIM + s * 32 + g * 8);
            acc0[jt] = __builtin_amdgcn_mfma_f32_16x16x32_bf16(a0, bf, acc0[jt], 0, 0, 0);
            acc1[jt] = __builtin_amdgcn_mfma_f32_16x16x32_bf16(a1, bf, acc1[jt], 0, 0, 0);
        }
    }

#pragma unroll
    for (int jt = 0; jt < 16; ++jt) {
        float bv = ADD_BIAS ? bias[jt * 16 + l15] : 0.f;
#pragma unroll
        for (int q = 0; q < 4; ++q) {
            int r0 = n0w + g * 4 + q;
            C[((size_t)b * N_DIM + r0) * F_DIM + jt * 16 + l15] = acc0[jt][q] + bv;
            int r1 = n0w + 16 + g * 4 + q;
            C[((size_t)b * N_DIM + r1) * F_DIM + jt * 16 + l15] = acc1[jt][q] + bv;
        }
    }
}

// ---------------------------------------------------------------------------
// k_spmm_bf16: x1 = relu(A_hat @ h1 + b1), scale fused. bf16 out. XCD remap.
// ---------------------------------------------------------------------------
__global__ __launch_bounds__(256) void k_spmm_bf16(const float* __restrict__ X,
                                                   const int* __restrict__ idxb,
                                                   const float* __restrict__ wbr,
                                                   const float* __restrict__ deg,
                                                   const float* __restrict__ bias,
                                                   unsigned short* __restrict__ Y) {
    const int lid = blockIdx.x;                 // 24576 blocks
    const int slot = lid >> 3;                  // 0..3071
    const int b = (lid & 7) + 8 * (slot >> 7);  // 24 batches per XCD
    const int rowblk = slot & 127;
    const int w = threadIdx.x >> 6;
    const int l = threadIdx.x & 63;
    const int row = b * N_DIM + rowblk * 4 + w;

    const float* Xb = X + ((size_t)b << 9) * F_DIM;
    const float* degb = deg + b * N_DIM;
    const int* id = idxb + row * K_TOP;
    const float* raw = wbr + row * (K_TOP + 1);

    const float dgs = deg[row];
    const float dn = (dgs == 0.f) ? 0.f : 1.f / sqrtf(dgs);
    float4 bv = ((const float4*)bias)[l];
    float4 xv = ((const float4*)(X + (size_t)row * F_DIM))[l];
    const float ws = dn * dn;
    float4 acc;
    acc.x = ws * xv.x + bv.x; acc.y = ws * xv.y + bv.y;
    acc.z = ws * xv.z + bv.z; acc.w = ws * xv.w + bv.w;
#pragma unroll
    for (int i = 0; i < K_TOP; ++i) {
        int m = id[i];
        float dgm = degb[m];
        float dm = (dgm == 0.f) ? 0.f : 1.f / sqrtf(dgm);
        float wi = dn * raw[i] * dm;
        float4 gv = ((const float4*)(Xb + ((size_t)m << 8)))[l];
        acc.x += wi * gv.x; acc.y += wi * gv.y;
        acc.z += wi * gv.z; acc.w += wi * gv.w;
    }
    acc.x = fmaxf(acc.x, 0.f); acc.y = fmaxf(acc.y, 0.f);
    acc.z = fmaxf(acc.z, 0.f); acc.w = fmaxf(acc.w, 0.f);
    uint2 p;
    p.x = (unsigned)f2bf(acc.x) | ((unsigned)f2bf(acc.y) << 16);
    p.y = (unsigned)f2bf(acc.z) | ((unsigned)f2bf(acc.w) << 16);
    ((uint2*)Y)[(size_t)row * (F_DIM / 4) + l] = p;
}

// ---------------------------------------------------------------------------
// k_spmm_trans: x2 = A_hat @ h2 + b2 (scale fused), then out = x2^T + v
// ---------------------------------------------------------------------------
__global__ __launch_bounds__(256) void k_spmm_trans(const float* __restrict__ X,
                                                    const int* __restrict__ idxb,
                                                    const float* __restrict__ wbr,
                                                    const float* __restrict__ deg,
                                                    const float* __restrict__ bias,
                                                    const float* __restrict__ v,
                                                    float* __restrict__ out) {
    __shared__ float tile[32][257];
    const int lid = blockIdx.x;                 // 3072 blocks
    const int slot = lid >> 3;                  // 0..383
    const int b = (lid & 7) + 8 * (slot >> 4);
    const int n0 = (slot & 15) * 32;
    const int w = threadIdx.x >> 6;
    const int l = threadIdx.x & 63;

    const float* Xb = X + ((size_t)b << 9) * F_DIM;
    const float* degb = deg + b * N_DIM;
    float4 bv = ((const float4*)bias)[l];

    for (int r8 = 0; r8 < 8; ++r8) {
        const int rloc = w * 8 + r8;
        const int row = b * N_DIM + n0 + rloc;
        const int* id = idxb + row * K_TOP;
        const float* raw = wbr + row * (K_TOP + 1);
        const float dgs = deg[row];
        const float dn = (dgs == 0.f) ? 0.f : 1.f / sqrtf(dgs);
        float4 xv = ((const float4*)(X + (size_t)row * F_DIM))[l];
        const float ws = dn * dn;
        float4 acc;
        acc.x = ws * xv.x + bv.x; acc.y = ws * xv.y + bv.y;
        acc.z = ws * xv.z + bv.z; acc.w = ws * xv.w + bv.w;
#pragma unroll
        for (int i = 0; i < K_TOP; ++i) {
            int m = id[i];
            float dgm = degb[m];
            float dm = (dgm == 0.f) ? 0.f : 1.f / sqrtf(dgm);
            float wi = dn * raw[i] * dm;
            float4 gv = ((const float4*)(Xb + ((size_t)m << 8)))[l];
            acc.x += wi * gv.x; acc.y += wi * gv.y;
            acc.z += wi * gv.z; acc.w += wi * gv.w;
        }
        tile[rloc][l * 4 + 0] = acc.x;
        tile[rloc][l * 4 + 1] = acc.y;
        tile[rloc][l * 4 + 2] = acc.z;
        tile[rloc][l * 4 + 3] = acc.w;
    }
    __syncthreads();

    const int i8 = l & 7;
    const int j8 = l >> 3;
#pragma unroll
    for (int k = 0; k < 8; ++k) {
        const int f = (k * 4 + w) * 8 + j8;
        const size_t vo = (size_t)b * F_DIM * N_DIM + (size_t)f * N_DIM + n0;
        float4 vv = ((const float4*)(v + vo))[i8];
        float4 o;
        o.x = tile[i8 * 4 + 0][f] + vv.x;
        o.y = tile[i8 * 4 + 1][f] + vv.y;
        o.z = tile[i8 * 4 + 2][f] + vv.z;
        o.w = tile[i8 * 4 + 3][f] + vv.w;
        ((float4*)(out + vo))[i8] = o;
    }
}

// ---------------------------------------------------------------------------
extern "C" void kernel_launch(void* const* d_in, const int* in_sizes, int n_in,
                              void* d_out, int out_size, void* d_ws, size_t ws_size,
                              hipStream_t stream) {
    const float* v   = (const float*)d_in[0];
    const float* g_w = (const float*)d_in[1];
    const float* g_b = (const float*)d_in[2];
    const float* w1  = (const float*)d_in[3];
    const float* b1  = (const float*)d_in[4];
    const float* w2  = (const float*)d_in[5];
    const float* b2  = (const float*)d_in[6];
    float* out = (float*)d_out;

    const size_t S = (size_t)B_DIM * N_DIM * F_DIM;
    float* bufA = (float*)d_ws;                     // h1, then h2 (fp32)
    float* bufB = bufA + S;                         // vt(bf16) -> x1bf(bf16)
    float* bc   = bufB + S;
    float* deg  = bc + F_DIM;
    float* wb   = deg + (size_t)B_DIM * N_DIM;      // raw top-10 values
    int*   idxb = (int*)(wb + (size_t)B_DIM * N_DIM * (K_TOP + 1));
    unsigned short* Wt1 = (unsigned short*)(idxb + (size_t)B_DIM * N_DIM * K_TOP);
    unsigned short* W2t = Wt1 + F_DIM * F_DIM;

    unsigned short* vt   = (unsigned short*)bufB;
    unsigned short* x1bf = (unsigned short*)bufB;   // overwrites vt (dead after gemm1)

    k_combine<<<dim3(2 * F_DIM + 2), 256, 0, stream>>>(g_w, g_b, w1, w2, Wt1, bc, W2t);
    k_to_bf16t<<<dim3(N_DIM / 32, F_DIM / 32, B_DIM), 256, 0, stream>>>(v, vt);
    k_topk_reg<<<dim3(N_DIM / 64, B_DIM), 256, 0, stream>>>(vt, deg, idxb, wb);
    // h1 = vt @ Wt1^T + bc -> bufA
    k_gemm_mfma<true><<<dim3(N_DIM / 128, B_DIM), 256, 0, stream>>>(vt, Wt1, bc, bufA);
    // x1 = relu(A_hat @ h1 + b1) -> x1bf (bf16), scale fused
    k_spmm_bf16<<<dim3(B_DIM * N_DIM / 4), 256, 0, stream>>>(bufA, idxb, wb, deg, b1, x1bf);
    // h2 = x1bf @ W2t^T -> bufA
    k_gemm_mfma<false><<<dim3(N_DIM / 128, B_DIM), 256, 0, stream>>>(x1bf, W2t, nullptr, bufA);
    // out = (A_hat @ h2 + b2)^T + v, scale+transpose+residual fused
    k_spmm_trans<<<dim3(B_DIM * N_DIM / 32), 256, 0, stream>>>(bufA, idxb, wb, deg, b2, v, out);
}

// Round 8
// 510.439 us; speedup vs baseline: 3.0110x; 1.0698x over previous
//
#include <hip/hip_runtime.h>
#include <float.h>

#define F_DIM 256
#define N_DIM 512
#define B_DIM 192
#define K_TOP 10

typedef __attribute__((ext_vector_type(8))) short short8;
typedef __attribute__((ext_vector_type(4))) float f32x4;

__device__ inline unsigned short f2bf(float x) {
    unsigned u = __builtin_bit_cast(unsigned, x);
    return (unsigned short)((u + 0x7fffu + ((u >> 16) & 1u)) >> 16);
}

// ---------------------------------------------------------------------------
// k_combine (grid 514):
//   bx<256 : Wt1[j][f=bx] = bf16( sum_h g_w[h,f]*w1[h,j] )
//   bx==256: bc[j] = sum_h g_b[h]*w1[h,j]
//   bx>256 : W2t[j][f] = bf16(w2[f][j])
// ---------------------------------------------------------------------------
__global__ __launch_bounds__(256) void k_combine(const float* __restrict__ g_w,
                                                 const float* __restrict__ g_b,
                                                 const float* __restrict__ w1,
                                                 const float* __restrict__ w2,
                                                 unsigned short* __restrict__ Wt1,
                                                 float* __restrict__ bc,
                                                 unsigned short* __restrict__ W2t) {
    const int j = threadIdx.x;
    const int bx = blockIdx.x;
    if (bx < F_DIM) {
        float acc = 0.f;
        for (int h = 0; h < F_DIM; ++h) acc += g_w[h * F_DIM + bx] * w1[h * F_DIM + j];
        Wt1[j * F_DIM + bx] = f2bf(acc);
    } else if (bx == F_DIM) {
        float acc = 0.f;
        for (int h = 0; h < F_DIM; ++h) acc += g_b[h] * w1[h * F_DIM + j];
        bc[j] = acc;
    } else {
        int f = bx - F_DIM - 1;
        W2t[j * F_DIM + f] = f2bf(w2[f * F_DIM + j]);
    }
}

// ---------------------------------------------------------------------------
// k_to_bf16t: vt[b][n][f] = bf16(v[b][f][n])
// ---------------------------------------------------------------------------
__global__ __launch_bounds__(256) void k_to_bf16t(const float* __restrict__ v,
                                                  unsigned short* __restrict__ vt) {
    __shared__ float tile[32][33];
    const int b = blockIdx.z;
    const int n0 = blockIdx.x * 32;
    const int f0 = blockIdx.y * 32;
    const int tx = threadIdx.x & 31, ty = threadIdx.x >> 5;
    const float* vb = v + (size_t)b * F_DIM * N_DIM;
#pragma unroll
    for (int q = 0; q < 4; ++q)
        tile[ty + q * 8][tx] = vb[(size_t)(f0 + ty + q * 8) * N_DIM + n0 + tx];
    __syncthreads();
    const int wn = threadIdx.x >> 4;
    const int wf = threadIdx.x & 15;
    unsigned* vt32 = (unsigned*)vt;
#pragma unroll
    for (int q2 = 0; q2 < 2; ++q2) {
        int row = wn + q2 * 16;
        unsigned lo = f2bf(tile[wf * 2][row]);
        unsigned hi = f2bf(tile[wf * 2 + 1][row]);
        vt32[(size_t)(b * N_DIM + n0 + row) * (F_DIM / 2) + (f0 >> 1) + wf] = lo | (hi << 16);
    }
}

// ---------------------------------------------------------------------------
// k_topk_reg: unchanged from R7 (LDS-staged MFMA + chunked tournament).
// ---------------------------------------------------------------------------
__global__ __launch_bounds__(256, 2) void k_topk_reg(const unsigned short* __restrict__ vt,
                                                     float* __restrict__ deg,
                                                     int* __restrict__ idxb,
                                                     float* __restrict__ wb) {
    __shared__ unsigned short stage[2][N_DIM * 32];   // 2 x 32 KB

    const int lid = blockIdx.y * 8 + blockIdx.x;
    const int slot = lid >> 3;
    const int b = (lid & 7) + 8 * (slot >> 3);
    const int nblk = slot & 7;

    const int w = threadIdx.x >> 6;
    const int l = threadIdx.x & 63;
    const int l15 = l & 15;
    const int g = l >> 4;
    const int n0w = nblk * 64 + w * 16;
    const unsigned short* vtb = vt + (size_t)b * N_DIM * F_DIM;

    short8 bf[8];
#pragma unroll
    for (int s = 0; s < 8; ++s)
        bf[s] = *(const short8*)(vtb + (size_t)(n0w + l15) * F_DIM + s * 32 + g * 8);

    f32x4 acc[32];
#pragma unroll
    for (int mt = 0; mt < 32; ++mt) acc[mt] = (f32x4){0.f, 0.f, 0.f, 0.f};

#define STAGE(c, bufi)                                                           \
    {                                                                            \
        _Pragma("unroll")                                                        \
        for (int k = 0; k < 8; ++k) {                                            \
            int sid = w * 512 + k * 64 + l;                                      \
            int row = sid >> 2;                                                  \
            int sl = sid & 3;                                                    \
            const unsigned short* src = vtb + (size_t)row * F_DIM + (c) * 32 +   \
                                        ((sl ^ ((row >> 1) & 3)) << 3);          \
            __builtin_amdgcn_global_load_lds(                                    \
                (const __attribute__((address_space(1))) void*)src,              \
                (__attribute__((address_space(3))) void*)(                       \
                    (char*)&stage[bufi][0] + (size_t)(w * 512 + k * 64) * 16),   \
                16, 0, 0);                                                       \
        }                                                                        \
    }

    STAGE(0, 0);
    asm volatile("s_waitcnt vmcnt(0)" ::: "memory");
    __syncthreads();

    const int slx = g ^ ((l15 >> 1) & 3);
    for (int c = 0; c < 8; ++c) {
        const int cur = c & 1;
        if (c < 7) STAGE(c + 1, cur ^ 1);
        const char* sb = (const char*)&stage[cur][0];
        short8 bcur = bf[c];
#pragma unroll
        for (int mt = 0; mt < 32; ++mt) {
            const int row = mt * 16 + l15;
            short8 a = *(const short8*)(sb + row * 64 + (slx << 4));
            acc[mt] = __builtin_amdgcn_mfma_f32_16x16x32_bf16(a, bcur, acc[mt], 0, 0, 0);
        }
        asm volatile("s_waitcnt vmcnt(0)" ::: "memory");
        __syncthreads();
    }
#undef STAGE

    const int row = b * N_DIM + n0w + l15;
    float sum = 0.f;
    for (int it = 0; it < K_TOP; ++it) {
        float chv[4]; int che[4];
#pragma unroll
        for (int c = 0; c < 4; ++c) {
            float tv[16]; int te[16];
#pragma unroll
            for (int p = 0; p < 16; ++p) {
                const int e0 = c * 32 + 2 * p, e1 = e0 + 1;
                float a = acc[e0 >> 2][e0 & 3];
                float bb2 = acc[e1 >> 2][e1 & 3];
                bool tk = bb2 > a;
                tv[p] = tk ? bb2 : a;
                te[p] = tk ? e1 : e0;
            }
#pragma unroll
            for (int len = 8; len >= 1; len >>= 1) {
#pragma unroll
                for (int i2 = 0; i2 < 8; ++i2) {
                    if (i2 < len) {
                        bool tk = tv[i2 + len] > tv[i2];
                        tv[i2] = tk ? tv[i2 + len] : tv[i2];
                        te[i2] = tk ? te[i2 + len] : te[i2];
                    }
                }
            }
            chv[c] = tv[0]; che[c] = te[0];
        }
        bool t1 = chv[1] > chv[0];
        float m0 = t1 ? chv[1] : chv[0]; int ea = t1 ? che[1] : che[0];
        bool t2 = chv[3] > chv[2];
        float m1 = t2 ? chv[3] : chv[2]; int eb = t2 ? che[3] : che[2];
        bool t3 = m1 > m0;
        float bv = t3 ? m1 : m0; int be = t3 ? eb : ea;
        int bm = ((be >> 2) << 4) | (g << 2) | (be & 3);

#pragma unroll
        for (int off = 16; off <= 32; off <<= 1) {
            float ov = __shfl_xor(bv, off, 64);
            int om = __shfl_xor(bm, off, 64);
            if (ov > bv || (ov == bv && om < bm)) { bv = ov; bm = om; }
        }
        sum += bv;
        if (l < 16) {
            idxb[row * K_TOP + it] = bm;
            wb[row * (K_TOP + 1) + it] = bv;
        }
        if (it < K_TOP - 1) {
            int eo = ((bm >> 4) << 2) | (bm & 3);
            eo = (((bm >> 2) & 3) == g) ? eo : 999;
#pragma unroll
            for (int e = 0; e < 128; ++e)
                acc[e >> 2][e & 3] = (e == eo) ? -FLT_MAX : acc[e >> 2][e & 3];
        }
    }
    if (l < 16) deg[row] = sum + 1.0f;
}

// ---------------------------------------------------------------------------
// k_scale: wbs[row][i] = dn * wb[row][i] * dm (i<10); wbs[row][10] = dn*dn.
// Identical op order to the previously-fused recompute (bit-identical).
// Stride 12 for alignment.
// ---------------------------------------------------------------------------
__global__ __launch_bounds__(256) void k_scale(const float* __restrict__ deg,
                                               const int* __restrict__ idxb,
                                               const float* __restrict__ wb,
                                               float* __restrict__ wbs) {
    const int row = blockIdx.x * 256 + threadIdx.x;
    const float dg = deg[row];
    const float dn = (dg == 0.f) ? 0.f : 1.f / sqrtf(dg);
    const int bb = (row >> 9) << 9;
#pragma unroll
    for (int i = 0; i < K_TOP; ++i) {
        int m = idxb[row * K_TOP + i];
        float dgm = deg[bb + m];
        float dm = (dgm == 0.f) ? 0.f : 1.f / sqrtf(dgm);
        wbs[row * 12 + i] = dn * wb[row * (K_TOP + 1) + i] * dm;
    }
    wbs[row * 12 + K_TOP] = dn * dn;
}

// ---------------------------------------------------------------------------
// k_gemm_mfma: per batch C[512,256] = At(bf16) @ Wt^T(bf16), register-direct
// ---------------------------------------------------------------------------
template <bool ADD_BIAS>
__global__ __launch_bounds__(256, 2) void k_gemm_mfma(const unsigned short* __restrict__ At,
                                                      const unsigned short* __restrict__ Wt,
                                                      const float* __restrict__ bias,
                                                      float* __restrict__ C) {
    const int b = blockIdx.y;
    const int w = threadIdx.x >> 6;
    const int l = threadIdx.x & 63;
    const int l15 = l & 15;
    const int g = l >> 4;
    const int n0w = blockIdx.x * 128 + w * 32;
    const unsigned short* Ab = At + (size_t)b * N_DIM * F_DIM;

    f32x4 acc0[16], acc1[16];
#pragma unroll
    for (int jt = 0; jt < 16; ++jt) {
        acc0[jt] = (f32x4){0.f, 0.f, 0.f, 0.f};
        acc1[jt] = (f32x4){0.f, 0.f, 0.f, 0.f};
    }

    for (int s = 0; s < 8; ++s) {
        short8 a0 = *(const short8*)(Ab + (size_t)(n0w + l15) * F_DIM + s * 32 + g * 8);
        short8 a1 = *(const short8*)(Ab + (size_t)(n0w + 16 + l15) * F_DIM + s * 32 + g * 8);
#pragma unroll
        for (int jt = 0; jt < 16; ++jt) {
            short8 bf = *(const short8*)(Wt + (size_t)(jt * 16 + l15) * F_DIM + s * 32 + g * 8);
            acc0[jt] = __builtin_amdgcn_mfma_f32_16x16x32_bf16(a0, bf, acc0[jt], 0, 0, 0);
            acc1[jt] = __builtin_amdgcn_mfma_f32_16x16x32_bf16(a1, bf, acc1[jt], 0, 0, 0);
        }
    }

#pragma unroll
    for (int jt = 0; jt < 16; ++jt) {
        float bv = ADD_BIAS ? bias[jt * 16 + l15] : 0.f;
#pragma unroll
        for (int q = 0; q < 4; ++q) {
            int r0 = n0w + g * 4 + q;
            C[((size_t)b * N_DIM + r0) * F_DIM + jt * 16 + l15] = acc0[jt][q] + bv;
            int r1 = n0w + 16 + g * 4 + q;
            C[((size_t)b * N_DIM + r1) * F_DIM + jt * 16 + l15] = acc1[jt][q] + bv;
        }
    }
}

// ---------------------------------------------------------------------------
// k_spmm_bf16: x1 = relu(A_hat @ h1 + b1) with PRE-SCALED weights. bf16 out.
// ---------------------------------------------------------------------------
__global__ __launch_bounds__(256) void k_spmm_bf16(const float* __restrict__ X,
                                                   const int* __restrict__ idxb,
                                                   const float* __restrict__ wbs,
                                                   const float* __restrict__ bias,
                                                   unsigned short* __restrict__ Y) {
    const int lid = blockIdx.x;                 // 24576 blocks
    const int slot = lid >> 3;                  // 0..3071
    const int b = (lid & 7) + 8 * (slot >> 7);  // 24 batches per XCD
    const int rowblk = slot & 127;
    const int w = threadIdx.x >> 6;
    const int l = threadIdx.x & 63;
    const int row = b * N_DIM + rowblk * 4 + w;

    const float* Xb = X + ((size_t)b << 9) * F_DIM;
    const int* id = idxb + row * K_TOP;
    const float* ww = wbs + (size_t)row * 12;

    float4 bv = ((const float4*)bias)[l];
    float4 xv = ((const float4*)(X + (size_t)row * F_DIM))[l];
    const float ws = ww[K_TOP];
    float4 acc;
    acc.x = ws * xv.x + bv.x; acc.y = ws * xv.y + bv.y;
    acc.z = ws * xv.z + bv.z; acc.w = ws * xv.w + bv.w;
#pragma unroll
    for (int i = 0; i < K_TOP; ++i) {
        float wi = ww[i];
        float4 gv = ((const float4*)(Xb + ((size_t)id[i] << 8)))[l];
        acc.x += wi * gv.x; acc.y += wi * gv.y;
        acc.z += wi * gv.z; acc.w += wi * gv.w;
    }
    acc.x = fmaxf(acc.x, 0.f); acc.y = fmaxf(acc.y, 0.f);
    acc.z = fmaxf(acc.z, 0.f); acc.w = fmaxf(acc.w, 0.f);
    uint2 p;
    p.x = (unsigned)f2bf(acc.x) | ((unsigned)f2bf(acc.y) << 16);
    p.y = (unsigned)f2bf(acc.z) | ((unsigned)f2bf(acc.w) << 16);
    ((uint2*)Y)[(size_t)row * (F_DIM / 4) + l] = p;
}

// ---------------------------------------------------------------------------
// k_spmm_trans: x2 = A_hat @ h2 + b2 (pre-scaled weights), out = x2^T + v.
// Two 16-row phases (LDS 16.6 KB -> 8 blocks/CU, 2x occupancy vs R7).
// ---------------------------------------------------------------------------
__global__ __launch_bounds__(256) void k_spmm_trans(const float* __restrict__ X,
                                                    const int* __restrict__ idxb,
                                                    const float* __restrict__ wbs,
                                                    const float* __restrict__ bias,
                                                    const float* __restrict__ v,
                                                    float* __restrict__ out) {
    __shared__ float tile[16][260];
    const int lid = blockIdx.x;                 // 3072 blocks
    const int slot = lid >> 3;                  // 0..383
    const int b = (lid & 7) + 8 * (slot >> 4);
    const int n0 = (slot & 15) * 32;
    const int w = threadIdx.x >> 6;
    const int l = threadIdx.x & 63;

    const float* Xb = X + ((size_t)b << 9) * F_DIM;
    float4 bv = ((const float4*)bias)[l];
    const int i4 = l & 3, fj = l >> 2;

    for (int p = 0; p < 2; ++p) {
        if (p) __syncthreads();                 // protect tile reuse
#pragma unroll
        for (int r4 = 0; r4 < 4; ++r4) {
            const int rloc = w * 4 + r4;
            const int row = b * N_DIM + n0 + p * 16 + rloc;
            const int* id = idxb + row * K_TOP;
            const float* ww = wbs + (size_t)row * 12;
            float4 xv = ((const float4*)(X + (size_t)row * F_DIM))[l];
            const float ws = ww[K_TOP];
            float4 acc;
            acc.x = ws * xv.x + bv.x; acc.y = ws * xv.y + bv.y;
            acc.z = ws * xv.z + bv.z; acc.w = ws * xv.w + bv.w;
#pragma unroll
            for (int i = 0; i < K_TOP; ++i) {
                float wi = ww[i];
                float4 gv = ((const float4*)(Xb + ((size_t)id[i] << 8)))[l];
                acc.x += wi * gv.x; acc.y += wi * gv.y;
                acc.z += wi * gv.z; acc.w += wi * gv.w;
            }
            tile[rloc][l * 4 + 0] = acc.x;
            tile[rloc][l * 4 + 1] = acc.y;
            tile[rloc][l * 4 + 2] = acc.z;
            tile[rloc][l * 4 + 3] = acc.w;
        }
        __syncthreads();
        // out: f = k*64 + w*16 + fj, n-quad i4 within this 16-n phase
#pragma unroll
        for (int k = 0; k < 4; ++k) {
            const int f = k * 64 + w * 16 + fj;
            const size_t vo = (size_t)b * F_DIM * N_DIM + (size_t)f * N_DIM + n0 + p * 16;
            float4 vv = ((const float4*)(v + vo))[i4];
            float4 o;
            o.x = tile[i4 * 4 + 0][f] + vv.x;
            o.y = tile[i4 * 4 + 1][f] + vv.y;
            o.z = tile[i4 * 4 + 2][f] + vv.z;
            o.w = tile[i4 * 4 + 3][f] + vv.w;
            ((float4*)(out + vo))[i4] = o;
        }
    }
}

// ---------------------------------------------------------------------------
extern "C" void kernel_launch(void* const* d_in, const int* in_sizes, int n_in,
                              void* d_out, int out_size, void* d_ws, size_t ws_size,
                              hipStream_t stream) {
    const float* v   = (const float*)d_in[0];
    const float* g_w = (const float*)d_in[1];
    const float* g_b = (const float*)d_in[2];
    const float* w1  = (const float*)d_in[3];
    const float* b1  = (const float*)d_in[4];
    const float* w2  = (const float*)d_in[5];
    const float* b2  = (const float*)d_in[6];
    float* out = (float*)d_out;

    const size_t S = (size_t)B_DIM * N_DIM * F_DIM;
    float* bufA = (float*)d_ws;                     // h1, then h2 (fp32)
    float* bufB = bufA + S;                         // vt/x1bf in lower 2S bytes
    float* bc   = bufB + S;
    float* deg  = bc + F_DIM;
    float* wb   = deg + (size_t)B_DIM * N_DIM;      // raw top-10 values
    int*   idxb = (int*)(wb + (size_t)B_DIM * N_DIM * (K_TOP + 1));
    unsigned short* Wt1 = (unsigned short*)(idxb + (size_t)B_DIM * N_DIM * K_TOP);
    unsigned short* W2t = Wt1 + F_DIM * F_DIM;

    unsigned short* vt   = (unsigned short*)bufB;   // lower half of bufB
    unsigned short* x1bf = (unsigned short*)bufB;
    float* wbs = bufB + S / 2;                      // upper half of bufB (free)

    k_combine<<<dim3(2 * F_DIM + 2), 256, 0, stream>>>(g_w, g_b, w1, w2, Wt1, bc, W2t);
    k_to_bf16t<<<dim3(N_DIM / 32, F_DIM / 32, B_DIM), 256, 0, stream>>>(v, vt);
    k_topk_reg<<<dim3(N_DIM / 64, B_DIM), 256, 0, stream>>>(vt, deg, idxb, wb);
    // pre-scale edge weights once (removes rsqrt chain from both spmm kernels)
    k_scale<<<dim3(B_DIM * N_DIM / 256), 256, 0, stream>>>(deg, idxb, wb, wbs);
    // h1 = vt @ Wt1^T + bc -> bufA
    k_gemm_mfma<true><<<dim3(N_DIM / 128, B_DIM), 256, 0, stream>>>(vt, Wt1, bc, bufA);
    // x1 = relu(A_hat @ h1 + b1) -> x1bf (bf16)
    k_spmm_bf16<<<dim3(B_DIM * N_DIM / 4), 256, 0, stream>>>(bufA, idxb, wbs, b1, x1bf);
    // h2 = x1bf @ W2t^T -> bufA
    k_gemm_mfma<false><<<dim3(N_DIM / 128, B_DIM), 256, 0, stream>>>(x1bf, W2t, nullptr, bufA);
    // out = (A_hat @ h2 + b2)^T + v
    k_spmm_trans<<<dim3(B_DIM * N_DIM / 32), 256, 0, stream>>>(bufA, idxb, wbs, b2, v, out);
}

// Round 9
// 462.423 us; speedup vs baseline: 3.3236x; 1.1038x over previous
//
#include <hip/hip_runtime.h>
#include <float.h>

#define F_DIM 256
#define N_DIM 512
#define B_DIM 192
#define K_TOP 10

typedef __attribute__((ext_vector_type(8))) short short8;
typedef __attribute__((ext_vector_type(4))) float f32x4;

__device__ inline unsigned short f2bf(float x) {
    unsigned u = __builtin_bit_cast(unsigned, x);
    return (unsigned short)((u + 0x7fffu + ((u >> 16) & 1u)) >> 16);
}

// ---------------------------------------------------------------------------
// k_combine (grid 514):
//   bx<256 : Wt1[j][f=bx] = bf16( sum_h g_w[h,f]*w1[h,j] )
//   bx==256: bc[j] = sum_h g_b[h]*w1[h,j]
//   bx>256 : W2t[j][f] = bf16(w2[f][j])
// ---------------------------------------------------------------------------
__global__ __launch_bounds__(256) void k_combine(const float* __restrict__ g_w,
                                                 const float* __restrict__ g_b,
                                                 const float* __restrict__ w1,
                                                 const float* __restrict__ w2,
                                                 unsigned short* __restrict__ Wt1,
                                                 float* __restrict__ bc,
                                                 unsigned short* __restrict__ W2t) {
    const int j = threadIdx.x;
    const int bx = blockIdx.x;
    if (bx < F_DIM) {
        float acc = 0.f;
        for (int h = 0; h < F_DIM; ++h) acc += g_w[h * F_DIM + bx] * w1[h * F_DIM + j];
        Wt1[j * F_DIM + bx] = f2bf(acc);
    } else if (bx == F_DIM) {
        float acc = 0.f;
        for (int h = 0; h < F_DIM; ++h) acc += g_b[h] * w1[h * F_DIM + j];
        bc[j] = acc;
    } else {
        int f = bx - F_DIM - 1;
        W2t[j * F_DIM + f] = f2bf(w2[f * F_DIM + j]);
    }
}

// ---------------------------------------------------------------------------
// k_to_bf16t: vt[b][n][f] = bf16(v[b][f][n])
// ---------------------------------------------------------------------------
__global__ __launch_bounds__(256) void k_to_bf16t(const float* __restrict__ v,
                                                  unsigned short* __restrict__ vt) {
    __shared__ float tile[32][33];
    const int b = blockIdx.z;
    const int n0 = blockIdx.x * 32;
    const int f0 = blockIdx.y * 32;
    const int tx = threadIdx.x & 31, ty = threadIdx.x >> 5;
    const float* vb = v + (size_t)b * F_DIM * N_DIM;
#pragma unroll
    for (int q = 0; q < 4; ++q)
        tile[ty + q * 8][tx] = vb[(size_t)(f0 + ty + q * 8) * N_DIM + n0 + tx];
    __syncthreads();
    const int wn = threadIdx.x >> 4;
    const int wf = threadIdx.x & 15;
    unsigned* vt32 = (unsigned*)vt;
#pragma unroll
    for (int q2 = 0; q2 < 2; ++q2) {
        int row = wn + q2 * 16;
        unsigned lo = f2bf(tile[wf * 2][row]);
        unsigned hi = f2bf(tile[wf * 2 + 1][row]);
        vt32[(size_t)(b * N_DIM + n0 + row) * (F_DIM / 2) + (f0 >> 1) + wf] = lo | (hi << 16);
    }
}

// ---------------------------------------------------------------------------
// k_topk_reg: unchanged from R7 (LDS-staged MFMA + chunked tournament).
// ---------------------------------------------------------------------------
__global__ __launch_bounds__(256, 2) void k_topk_reg(const unsigned short* __restrict__ vt,
                                                     float* __restrict__ deg,
                                                     int* __restrict__ idxb,
                                                     float* __restrict__ wb) {
    __shared__ unsigned short stage[2][N_DIM * 32];   // 2 x 32 KB

    const int lid = blockIdx.y * 8 + blockIdx.x;
    const int slot = lid >> 3;
    const int b = (lid & 7) + 8 * (slot >> 3);
    const int nblk = slot & 7;

    const int w = threadIdx.x >> 6;
    const int l = threadIdx.x & 63;
    const int l15 = l & 15;
    const int g = l >> 4;
    const int n0w = nblk * 64 + w * 16;
    const unsigned short* vtb = vt + (size_t)b * N_DIM * F_DIM;

    short8 bf[8];
#pragma unroll
    for (int s = 0; s < 8; ++s)
        bf[s] = *(const short8*)(vtb + (size_t)(n0w + l15) * F_DIM + s * 32 + g * 8);

    f32x4 acc[32];
#pragma unroll
    for (int mt = 0; mt < 32; ++mt) acc[mt] = (f32x4){0.f, 0.f, 0.f, 0.f};

#define STAGE(c, bufi)                                                           \
    {                                                                            \
        _Pragma("unroll")                                                        \
        for (int k = 0; k < 8; ++k) {                                            \
            int sid = w * 512 + k * 64 + l;                                      \
            int row = sid >> 2;                                                  \
            int sl = sid & 3;                                                    \
            const unsigned short* src = vtb + (size_t)row * F_DIM + (c) * 32 +   \
                                        ((sl ^ ((row >> 1) & 3)) << 3);          \
            __builtin_amdgcn_global_load_lds(                                    \
                (const __attribute__((address_space(1))) void*)src,              \
                (__attribute__((address_space(3))) void*)(                       \
                    (char*)&stage[bufi][0] + (size_t)(w * 512 + k * 64) * 16),   \
                16, 0, 0);                                                       \
        }                                                                        \
    }

    STAGE(0, 0);
    asm volatile("s_waitcnt vmcnt(0)" ::: "memory");
    __syncthreads();

    const int slx = g ^ ((l15 >> 1) & 3);
    for (int c = 0; c < 8; ++c) {
        const int cur = c & 1;
        if (c < 7) STAGE(c + 1, cur ^ 1);
        const char* sb = (const char*)&stage[cur][0];
        short8 bcur = bf[c];
#pragma unroll
        for (int mt = 0; mt < 32; ++mt) {
            const int row = mt * 16 + l15;
            short8 a = *(const short8*)(sb + row * 64 + (slx << 4));
            acc[mt] = __builtin_amdgcn_mfma_f32_16x16x32_bf16(a, bcur, acc[mt], 0, 0, 0);
        }
        asm volatile("s_waitcnt vmcnt(0)" ::: "memory");
        __syncthreads();
    }
#undef STAGE

    const int row = b * N_DIM + n0w + l15;
    float sum = 0.f;
    for (int it = 0; it < K_TOP; ++it) {
        float chv[4]; int che[4];
#pragma unroll
        for (int c = 0; c < 4; ++c) {
            float tv[16]; int te[16];
#pragma unroll
            for (int p = 0; p < 16; ++p) {
                const int e0 = c * 32 + 2 * p, e1 = e0 + 1;
                float a = acc[e0 >> 2][e0 & 3];
                float bb2 = acc[e1 >> 2][e1 & 3];
                bool tk = bb2 > a;
                tv[p] = tk ? bb2 : a;
                te[p] = tk ? e1 : e0;
            }
#pragma unroll
            for (int len = 8; len >= 1; len >>= 1) {
#pragma unroll
                for (int i2 = 0; i2 < 8; ++i2) {
                    if (i2 < len) {
                        bool tk = tv[i2 + len] > tv[i2];
                        tv[i2] = tk ? tv[i2 + len] : tv[i2];
                        te[i2] = tk ? te[i2 + len] : te[i2];
                    }
                }
            }
            chv[c] = tv[0]; che[c] = te[0];
        }
        bool t1 = chv[1] > chv[0];
        float m0 = t1 ? chv[1] : chv[0]; int ea = t1 ? che[1] : che[0];
        bool t2 = chv[3] > chv[2];
        float m1 = t2 ? chv[3] : chv[2]; int eb = t2 ? che[3] : che[2];
        bool t3 = m1 > m0;
        float bv = t3 ? m1 : m0; int be = t3 ? eb : ea;
        int bm = ((be >> 2) << 4) | (g << 2) | (be & 3);

#pragma unroll
        for (int off = 16; off <= 32; off <<= 1) {
            float ov = __shfl_xor(bv, off, 64);
            int om = __shfl_xor(bm, off, 64);
            if (ov > bv || (ov == bv && om < bm)) { bv = ov; bm = om; }
        }
        sum += bv;
        if (l < 16) {
            idxb[row * K_TOP + it] = bm;
            wb[row * (K_TOP + 1) + it] = bv;
        }
        if (it < K_TOP - 1) {
            int eo = ((bm >> 4) << 2) | (bm & 3);
            eo = (((bm >> 2) & 3) == g) ? eo : 999;
#pragma unroll
            for (int e = 0; e < 128; ++e)
                acc[e >> 2][e & 3] = (e == eo) ? -FLT_MAX : acc[e >> 2][e & 3];
        }
    }
    if (l < 16) deg[row] = sum + 1.0f;
}

// ---------------------------------------------------------------------------
// k_scale: wbs[row][i] = dn * wb[row][i] * dm (i<10); wbs[row][10] = dn*dn.
// ---------------------------------------------------------------------------
__global__ __launch_bounds__(256) void k_scale(const float* __restrict__ deg,
                                               const int* __restrict__ idxb,
                                               const float* __restrict__ wb,
                                               float* __restrict__ wbs) {
    const int row = blockIdx.x * 256 + threadIdx.x;
    const float dg = deg[row];
    const float dn = (dg == 0.f) ? 0.f : 1.f / sqrtf(dg);
    const int bb = (row >> 9) << 9;
#pragma unroll
    for (int i = 0; i < K_TOP; ++i) {
        int m = idxb[row * K_TOP + i];
        float dgm = deg[bb + m];
        float dm = (dgm == 0.f) ? 0.f : 1.f / sqrtf(dgm);
        wbs[row * 12 + i] = dn * wb[row * (K_TOP + 1) + i] * dm;
    }
    wbs[row * 12 + K_TOP] = dn * dn;
}

// ---------------------------------------------------------------------------
// k_gemm_mfma: per batch C[512,256] = At(bf16) @ Wt^T(bf16), register-direct
// ---------------------------------------------------------------------------
template <bool ADD_BIAS>
__global__ __launch_bounds__(256, 2) void k_gemm_mfma(const unsigned short* __restrict__ At,
                                                      const unsigned short* __restrict__ Wt,
                                                      const float* __restrict__ bias,
                                                      float* __restrict__ C) {
    const int b = blockIdx.y;
    const int w = threadIdx.x >> 6;
    const int l = threadIdx.x & 63;
    const int l15 = l & 15;
    const int g = l >> 4;
    const int n0w = blockIdx.x * 128 + w * 32;
    const unsigned short* Ab = At + (size_t)b * N_DIM * F_DIM;

    f32x4 acc0[16], acc1[16];
#pragma unroll
    for (int jt = 0; jt < 16; ++jt) {
        acc0[jt] = (f32x4){0.f, 0.f, 0.f, 0.f};
        acc1[jt] = (f32x4){0.f, 0.f, 0.f, 0.f};
    }

    for (int s = 0; s < 8; ++s) {
        short8 a0 = *(const short8*)(Ab + (size_t)(n0w + l15) * F_DIM + s * 32 + g * 8);
        short8 a1 = *(const short8*)(Ab + (size_t)(n0w + 16 + l15) * F_DIM + s * 32 + g * 8);
#pragma unroll
        for (int jt = 0; jt < 16; ++jt) {
            short8 bf = *(const short8*)(Wt + (size_t)(jt * 16 + l15) * F_DIM + s * 32 + g * 8);
            acc0[jt] = __builtin_amdgcn_mfma_f32_16x16x32_bf16(a0, bf, acc0[jt], 0, 0, 0);
            acc1[jt] = __builtin_amdgcn_mfma_f32_16x16x32_bf16(a1, bf, acc1[jt], 0, 0, 0);
        }
    }

#pragma unroll
    for (int jt = 0; jt < 16; ++jt) {
        float bv = ADD_BIAS ? bias[jt * 16 + l15] : 0.f;
#pragma unroll
        for (int q = 0; q < 4; ++q) {
            int r0 = n0w + g * 4 + q;
            C[((size_t)b * N_DIM + r0) * F_DIM + jt * 16 + l15] = acc0[jt][q] + bv;
            int r1 = n0w + 16 + g * 4 + q;
            C[((size_t)b * N_DIM + r1) * F_DIM + jt * 16 + l15] = acc1[jt][q] + bv;
        }
    }
}

// ---------------------------------------------------------------------------
// k_spmm_bf16: x1 = relu(A_hat @ h1 + b1) with PRE-SCALED weights. bf16 out.
// ---------------------------------------------------------------------------
__global__ __launch_bounds__(256) void k_spmm_bf16(const float* __restrict__ X,
                                                   const int* __restrict__ idxb,
                                                   const float* __restrict__ wbs,
                                                   const float* __restrict__ bias,
                                                   unsigned short* __restrict__ Y) {
    const int lid = blockIdx.x;                 // 24576 blocks
    const int slot = lid >> 3;                  // 0..3071
    const int b = (lid & 7) + 8 * (slot >> 7);  // 2 batches/XCD concurrent
    const int rowblk = slot & 127;
    const int w = threadIdx.x >> 6;
    const int l = threadIdx.x & 63;
    const int row = b * N_DIM + rowblk * 4 + w;

    const float* Xb = X + ((size_t)b << 9) * F_DIM;
    const int* id = idxb + row * K_TOP;
    const float* ww = wbs + (size_t)row * 12;

    float4 bv = ((const float4*)bias)[l];
    float4 xv = ((const float4*)(X + (size_t)row * F_DIM))[l];
    const float ws = ww[K_TOP];
    float4 acc;
    acc.x = ws * xv.x + bv.x; acc.y = ws * xv.y + bv.y;
    acc.z = ws * xv.z + bv.z; acc.w = ws * xv.w + bv.w;
#pragma unroll
    for (int i = 0; i < K_TOP; ++i) {
        float wi = ww[i];
        float4 gv = ((const float4*)(Xb + ((size_t)id[i] << 8)))[l];
        acc.x += wi * gv.x; acc.y += wi * gv.y;
        acc.z += wi * gv.z; acc.w += wi * gv.w;
    }
    acc.x = fmaxf(acc.x, 0.f); acc.y = fmaxf(acc.y, 0.f);
    acc.z = fmaxf(acc.z, 0.f); acc.w = fmaxf(acc.w, 0.f);
    uint2 p;
    p.x = (unsigned)f2bf(acc.x) | ((unsigned)f2bf(acc.y) << 16);
    p.y = (unsigned)f2bf(acc.z) | ((unsigned)f2bf(acc.w) << 16);
    ((uint2*)Y)[(size_t)row * (F_DIM / 4) + l] = p;
}

// ---------------------------------------------------------------------------
// k_spmm_trans: x2 = A_hat @ h2 + b2 (pre-scaled weights), out = x2^T + v.
// Block = 16 rows x 128-f half-panel (64 tiles/batch -> 4 batches/XCD
// concurrent = 1 MB << L2, kills the 2.9x h2 refetch). LDS tile 8.25 KB.
// ---------------------------------------------------------------------------
__global__ __launch_bounds__(256) void k_spmm_trans(const float* __restrict__ X,
                                                    const int* __restrict__ idxb,
                                                    const float* __restrict__ wbs,
                                                    const float* __restrict__ bias,
                                                    const float* __restrict__ v,
                                                    float* __restrict__ out) {
    __shared__ float tile[16][132];
    const int lid = blockIdx.x;                 // 12288 blocks
    const int slot = lid >> 3;                  // 0..1535
    const int b = (lid & 7) + 8 * (slot >> 6);  // 64 tiles/batch
    const int tl = slot & 63;
    const int n0 = (tl & 31) * 16;
    const int f0 = (tl >> 5) * 128;
    const int w = threadIdx.x >> 6;
    const int l = threadIdx.x & 63;

    const float* Xb = X + ((size_t)b << 9) * F_DIM;
    const int rl = l >> 5;                      // row sub-index (0/1)
    const int fq = l & 31;                      // f-quad within half-panel
    float4 bv = ((const float4*)bias)[(f0 >> 2) + fq];

    // gather: 8 rows per pass (2 per wave), 2 passes; 512B-coalesced reads
    for (int p2 = 0; p2 < 2; ++p2) {
        const int rloc = p2 * 8 + w * 2 + rl;
        const int row = b * N_DIM + n0 + rloc;
        const int* id = idxb + row * K_TOP;
        const float* ww = wbs + (size_t)row * 12;
        float4 xv = ((const float4*)(X + (size_t)row * F_DIM + f0))[fq];
        const float ws = ww[K_TOP];
        float4 acc;
        acc.x = ws * xv.x + bv.x; acc.y = ws * xv.y + bv.y;
        acc.z = ws * xv.z + bv.z; acc.w = ws * xv.w + bv.w;
#pragma unroll
        for (int i = 0; i < K_TOP; ++i) {
            float wi = ww[i];
            float4 gv = ((const float4*)(Xb + ((size_t)id[i] << 8) + f0))[fq];
            acc.x += wi * gv.x; acc.y += wi * gv.y;
            acc.z += wi * gv.z; acc.w += wi * gv.w;
        }
        tile[rloc][fq * 4 + 0] = acc.x;
        tile[rloc][fq * 4 + 1] = acc.y;
        tile[rloc][fq * 4 + 2] = acc.z;
        tile[rloc][fq * 4 + 3] = acc.w;
    }
    __syncthreads();

    // transpose + residual: f = f0 + k*64 + w*16 + fj, n-quad i4
    const int i4 = l & 3, fj = l >> 2;
#pragma unroll
    for (int k = 0; k < 2; ++k) {
        const int fl = k * 64 + w * 16 + fj;
        const size_t vo = (size_t)b * F_DIM * N_DIM + (size_t)(f0 + fl) * N_DIM + n0;
        float4 vv = ((const float4*)(v + vo))[i4];
        float4 o;
        o.x = tile[i4 * 4 + 0][fl] + vv.x;
        o.y = tile[i4 * 4 + 1][fl] + vv.y;
        o.z = tile[i4 * 4 + 2][fl] + vv.z;
        o.w = tile[i4 * 4 + 3][fl] + vv.w;
        ((float4*)(out + vo))[i4] = o;
    }
}

// ---------------------------------------------------------------------------
extern "C" void kernel_launch(void* const* d_in, const int* in_sizes, int n_in,
                              void* d_out, int out_size, void* d_ws, size_t ws_size,
                              hipStream_t stream) {
    const float* v   = (const float*)d_in[0];
    const float* g_w = (const float*)d_in[1];
    const float* g_b = (const float*)d_in[2];
    const float* w1  = (const float*)d_in[3];
    const float* b1  = (const float*)d_in[4];
    const float* w2  = (const float*)d_in[5];
    const float* b2  = (const float*)d_in[6];
    float* out = (float*)d_out;

    const size_t S = (size_t)B_DIM * N_DIM * F_DIM;
    float* bufA = (float*)d_ws;                     // h1, then h2 (fp32)
    float* bufB = bufA + S;                         // vt/x1bf in lower half
    float* bc   = bufB + S;
    float* deg  = bc + F_DIM;
    float* wb   = deg + (size_t)B_DIM * N_DIM;      // raw top-10 values
    int*   idxb = (int*)(wb + (size_t)B_DIM * N_DIM * (K_TOP + 1));
    unsigned short* Wt1 = (unsigned short*)(idxb + (size_t)B_DIM * N_DIM * K_TOP);
    unsigned short* W2t = Wt1 + F_DIM * F_DIM;

    unsigned short* vt   = (unsigned short*)bufB;   // lower half of bufB
    unsigned short* x1bf = (unsigned short*)bufB;
    float* wbs = bufB + S / 2;                      // upper half of bufB (free)

    k_combine<<<dim3(2 * F_DIM + 2), 256, 0, stream>>>(g_w, g_b, w1, w2, Wt1, bc, W2t);
    k_to_bf16t<<<dim3(N_DIM / 32, F_DIM / 32, B_DIM), 256, 0, stream>>>(v, vt);
    k_topk_reg<<<dim3(N_DIM / 64, B_DIM), 256, 0, stream>>>(vt, deg, idxb, wb);
    // pre-scale edge weights once
    k_scale<<<dim3(B_DIM * N_DIM / 256), 256, 0, stream>>>(deg, idxb, wb, wbs);
    // h1 = vt @ Wt1^T + bc -> bufA
    k_gemm_mfma<true><<<dim3(N_DIM / 128, B_DIM), 256, 0, stream>>>(vt, Wt1, bc, bufA);
    // x1 = relu(A_hat @ h1 + b1) -> x1bf (bf16)
    k_spmm_bf16<<<dim3(B_DIM * N_DIM / 4), 256, 0, stream>>>(bufA, idxb, wbs, b1, x1bf);
    // h2 = x1bf @ W2t^T -> bufA
    k_gemm_mfma<false><<<dim3(N_DIM / 128, B_DIM), 256, 0, stream>>>(x1bf, W2t, nullptr, bufA);
    // out = (A_hat @ h2 + b2)^T + v  (16n x 128f tiles, L2-resident gather)
    k_spmm_trans<<<dim3(B_DIM * N_DIM / 16 * 2), 256, 0, stream>>>(bufA, idxb, wbs, b2, v, out);
}

// Round 10
// 455.553 us; speedup vs baseline: 3.3737x; 1.0151x over previous
//
#include <hip/hip_runtime.h>
#include <float.h>

#define F_DIM 256
#define N_DIM 512
#define B_DIM 192
#define K_TOP 10

typedef __attribute__((ext_vector_type(8))) short short8;
typedef __attribute__((ext_vector_type(4))) float f32x4;

__device__ inline unsigned short f2bf(float x) {
    unsigned u = __builtin_bit_cast(unsigned, x);
    return (unsigned short)((u + 0x7fffu + ((u >> 16) & 1u)) >> 16);
}

// ---------------------------------------------------------------------------
// k_combine (grid 514):
//   bx<256 : Wt1[j][f=bx] = bf16( sum_h g_w[h,f]*w1[h,j] )
//   bx==256: bc[j] = sum_h g_b[h]*w1[h,j]
//   bx>256 : W2t[j][f] = bf16(w2[f][j])
// ---------------------------------------------------------------------------
__global__ __launch_bounds__(256) void k_combine(const float* __restrict__ g_w,
                                                 const float* __restrict__ g_b,
                                                 const float* __restrict__ w1,
                                                 const float* __restrict__ w2,
                                                 unsigned short* __restrict__ Wt1,
                                                 float* __restrict__ bc,
                                                 unsigned short* __restrict__ W2t) {
    const int j = threadIdx.x;
    const int bx = blockIdx.x;
    if (bx < F_DIM) {
        float acc = 0.f;
        for (int h = 0; h < F_DIM; ++h) acc += g_w[h * F_DIM + bx] * w1[h * F_DIM + j];
        Wt1[j * F_DIM + bx] = f2bf(acc);
    } else if (bx == F_DIM) {
        float acc = 0.f;
        for (int h = 0; h < F_DIM; ++h) acc += g_b[h] * w1[h * F_DIM + j];
        bc[j] = acc;
    } else {
        int f = bx - F_DIM - 1;
        W2t[j * F_DIM + f] = f2bf(w2[f * F_DIM + j]);
    }
}

// ---------------------------------------------------------------------------
// k_to_bf16t: vt[b][n][f] = bf16(v[b][f][n])
// ---------------------------------------------------------------------------
__global__ __launch_bounds__(256) void k_to_bf16t(const float* __restrict__ v,
                                                  unsigned short* __restrict__ vt) {
    __shared__ float tile[32][33];
    const int b = blockIdx.z;
    const int n0 = blockIdx.x * 32;
    const int f0 = blockIdx.y * 32;
    const int tx = threadIdx.x & 31, ty = threadIdx.x >> 5;
    const float* vb = v + (size_t)b * F_DIM * N_DIM;
#pragma unroll
    for (int q = 0; q < 4; ++q)
        tile[ty + q * 8][tx] = vb[(size_t)(f0 + ty + q * 8) * N_DIM + n0 + tx];
    __syncthreads();
    const int wn = threadIdx.x >> 4;
    const int wf = threadIdx.x & 15;
    unsigned* vt32 = (unsigned*)vt;
#pragma unroll
    for (int q2 = 0; q2 < 2; ++q2) {
        int row = wn + q2 * 16;
        unsigned lo = f2bf(tile[wf * 2][row]);
        unsigned hi = f2bf(tile[wf * 2 + 1][row]);
        vt32[(size_t)(b * N_DIM + n0 + row) * (F_DIM / 2) + (f0 >> 1) + wf] = lo | (hi << 16);
    }
}

// ---------------------------------------------------------------------------
// k_topk_reg v3: block = 32 n-rows, 4 waves; wave w owns m in [w*128,w*128+128).
// acc = 8 mt x 2 nt x f32x4 = 64 regs -> 4 waves/SIMD (launch_bounds(256,4)).
// Single-buffer 32KB staged panel chunk; cross-wave top-10 merge via 1KB LDS
// scratch with lexicographic (value, global-m) compare -- bit-identical to R9
// selection semantics (associative max + lowest-m tie-break + same knockout).
// ---------------------------------------------------------------------------
__global__ __launch_bounds__(256, 4) void k_topk_reg(const unsigned short* __restrict__ vt,
                                                     float* __restrict__ deg,
                                                     int* __restrict__ idxb,
                                                     float* __restrict__ wb) {
    __shared__ unsigned short stage[N_DIM * 32];   // 32 KB: one 512x32 chunk
    __shared__ uint2 scr[32][4];                   // [row][wave] candidates

    const int lid = blockIdx.x;                    // 3072 blocks
    const int slot = lid >> 3;                     // 0..383
    const int b = (lid & 7) + 8 * (slot >> 4);     // 24 batches per XCD
    const int n0 = (slot & 15) * 32;

    const int w = threadIdx.x >> 6;
    const int l = threadIdx.x & 63;
    const int l15 = l & 15;
    const int g = l >> 4;
    const int mbase = w * 128;
    const unsigned short* vtb = vt + (size_t)b * N_DIM * F_DIM;

    f32x4 acc[8][2];
#pragma unroll
    for (int mt = 0; mt < 8; ++mt) {
        acc[mt][0] = (f32x4){0.f, 0.f, 0.f, 0.f};
        acc[mt][1] = (f32x4){0.f, 0.f, 0.f, 0.f};
    }

#define STAGE(c)                                                                 \
    {                                                                            \
        _Pragma("unroll")                                                        \
        for (int k = 0; k < 8; ++k) {                                            \
            int sid = w * 512 + k * 64 + l;                                      \
            int row = sid >> 2;                                                  \
            int sl = sid & 3;                                                    \
            const unsigned short* src = vtb + (size_t)row * F_DIM + (c) * 32 +   \
                                        ((sl ^ ((row >> 1) & 3)) << 3);          \
            __builtin_amdgcn_global_load_lds(                                    \
                (const __attribute__((address_space(1))) void*)src,              \
                (__attribute__((address_space(3))) void*)(                       \
                    (char*)&stage[0] + (size_t)sid * 16),                        \
                16, 0, 0);                                                       \
        }                                                                        \
    }

    const int slx = g ^ ((l15 >> 1) & 3);
    for (int c = 0; c < 8; ++c) {
        STAGE(c);
        asm volatile("s_waitcnt vmcnt(0)" ::: "memory");
        __syncthreads();
        const char* sb = (const char*)&stage[0];
        short8 b0 = *(const short8*)(sb + (n0 + l15) * 64 + (slx << 4));
        short8 b1 = *(const short8*)(sb + (n0 + 16 + l15) * 64 + (slx << 4));
#pragma unroll
        for (int mt = 0; mt < 8; ++mt) {
            const int mrow = mbase + mt * 16 + l15;
            short8 a = *(const short8*)(sb + mrow * 64 + (slx << 4));
            acc[mt][0] = __builtin_amdgcn_mfma_f32_16x16x32_bf16(a, b0, acc[mt][0], 0, 0, 0);
            acc[mt][1] = __builtin_amdgcn_mfma_f32_16x16x32_bf16(a, b1, acc[mt][1], 0, 0, 0);
        }
        __syncthreads();   // before next STAGE overwrites the buffer
    }
#undef STAGE

    // ---- top-10: rows r0 = n0+l15 (nt=0), r1 = n0+16+l15 (nt=1) ----
    const int grow0 = b * N_DIM + n0 + l15;
    float sum0 = 0.f, sum1 = 0.f;
    for (int it = 0; it < K_TOP; ++it) {
        float cv[2]; int cm[2];
#pragma unroll
        for (int nt = 0; nt < 2; ++nt) {
            float tv[16]; int te[16];
#pragma unroll
            for (int p = 0; p < 16; ++p) {
                const int e0 = 2 * p, e1 = 2 * p + 1;
                float a = acc[e0 >> 2][nt][e0 & 3];
                float bb2 = acc[e1 >> 2][nt][e1 & 3];
                bool tk = bb2 > a;                 // keep lower e on tie
                tv[p] = tk ? bb2 : a;
                te[p] = tk ? e1 : e0;
            }
#pragma unroll
            for (int len = 8; len >= 1; len >>= 1) {
#pragma unroll
                for (int i2 = 0; i2 < 8; ++i2) {
                    if (i2 < len) {
                        bool tk = tv[i2 + len] > tv[i2];
                        tv[i2] = tk ? tv[i2 + len] : tv[i2];
                        te[i2] = tk ? te[i2 + len] : te[i2];
                    }
                }
            }
            cv[nt] = tv[0];
            cm[nt] = mbase + ((te[0] >> 2) << 4) + (g << 2) + (te[0] & 3);
        }
        // cross-g reduce within wave (global-m tie-break)
#pragma unroll
        for (int off = 16; off <= 32; off <<= 1) {
#pragma unroll
            for (int nt = 0; nt < 2; ++nt) {
                float ov = __shfl_xor(cv[nt], off, 64);
                int om = __shfl_xor(cm[nt], off, 64);
                if (ov > cv[nt] || (ov == cv[nt] && om < cm[nt])) { cv[nt] = ov; cm[nt] = om; }
            }
        }
        // wave candidates -> scratch
        if (l < 16) {
            scr[l15][w] = make_uint2(__builtin_bit_cast(unsigned, cv[0]), (unsigned)cm[0]);
            scr[16 + l15][w] = make_uint2(__builtin_bit_cast(unsigned, cv[1]), (unsigned)cm[1]);
        }
        __syncthreads();
        // redundant 4-way merge per row (waves in ascending-m order)
        float wv[2]; int wm[2];
#pragma unroll
        for (int nt = 0; nt < 2; ++nt) {
            const uint2* sr = &scr[nt * 16 + l15][0];
            uint4 q01 = *(const uint4*)&sr[0];
            uint4 q23 = *(const uint4*)&sr[2];
            float v0 = __builtin_bit_cast(float, q01.x); int m0 = (int)q01.y;
            float v1 = __builtin_bit_cast(float, q01.z); int m1 = (int)q01.w;
            float v2 = __builtin_bit_cast(float, q23.x); int m2 = (int)q23.y;
            float v3 = __builtin_bit_cast(float, q23.z); int m3 = (int)q23.w;
            bool t1 = (v1 > v0) || (v1 == v0 && m1 < m0);
            float va = t1 ? v1 : v0; int ma = t1 ? m1 : m0;
            bool t2 = (v3 > v2) || (v3 == v2 && m3 < m2);
            float vb2 = t2 ? v3 : v2; int mb = t2 ? m3 : m2;
            bool t3 = (vb2 > va) || (vb2 == va && mb < ma);
            wv[nt] = t3 ? vb2 : va; wm[nt] = t3 ? mb : ma;
        }
        __syncthreads();   // scratch reusable next iteration
        sum0 += wv[0]; sum1 += wv[1];
        if (w == 0 && l < 16) {
            idxb[grow0 * K_TOP + it] = wm[0];
            wb[grow0 * (K_TOP + 1) + it] = wv[0];
            idxb[(grow0 + 16) * K_TOP + it] = wm[1];
            wb[(grow0 + 16) * (K_TOP + 1) + it] = wv[1];
        }
        if (it < K_TOP - 1) {
#pragma unroll
            for (int nt = 0; nt < 2; ++nt) {
                const int mwin = wm[nt];
                const bool own = ((mwin >> 7) == w) && (((mwin >> 2) & 3) == g);
                const int eo = (((mwin >> 4) & 7) << 2) | (mwin & 3);
#pragma unroll
                for (int ee = 0; ee < 32; ++ee)
                    acc[ee >> 2][nt][ee & 3] =
                        (own && ee == eo) ? -FLT_MAX : acc[ee >> 2][nt][ee & 3];
            }
        }
    }
    if (w == 0 && l < 16) {
        deg[grow0] = sum0 + 1.0f;
        deg[grow0 + 16] = sum1 + 1.0f;
    }
}

// ---------------------------------------------------------------------------
// k_scale: wbs[row][i] = dn * wb[row][i] * dm (i<10); wbs[row][10] = dn*dn.
// ---------------------------------------------------------------------------
__global__ __launch_bounds__(256) void k_scale(const float* __restrict__ deg,
                                               const int* __restrict__ idxb,
                                               const float* __restrict__ wb,
                                               float* __restrict__ wbs) {
    const int row = blockIdx.x * 256 + threadIdx.x;
    const float dg = deg[row];
    const float dn = (dg == 0.f) ? 0.f : 1.f / sqrtf(dg);
    const int bb = (row >> 9) << 9;
#pragma unroll
    for (int i = 0; i < K_TOP; ++i) {
        int m = idxb[row * K_TOP + i];
        float dgm = deg[bb + m];
        float dm = (dgm == 0.f) ? 0.f : 1.f / sqrtf(dgm);
        wbs[row * 12 + i] = dn * wb[row * (K_TOP + 1) + i] * dm;
    }
    wbs[row * 12 + K_TOP] = dn * dn;
}

// ---------------------------------------------------------------------------
// k_gemm_mfma: per batch C[512,256] = At(bf16) @ Wt^T(bf16), register-direct
// ---------------------------------------------------------------------------
template <bool ADD_BIAS>
__global__ __launch_bounds__(256, 2) void k_gemm_mfma(const unsigned short* __restrict__ At,
                                                      const unsigned short* __restrict__ Wt,
                                                      const float* __restrict__ bias,
                                                      float* __restrict__ C) {
    const int b = blockIdx.y;
    const int w = threadIdx.x >> 6;
    const int l = threadIdx.x & 63;
    const int l15 = l & 15;
    const int g = l >> 4;
    const int n0w = blockIdx.x * 128 + w * 32;
    const unsigned short* Ab = At + (size_t)b * N_DIM * F_DIM;

    f32x4 acc0[16], acc1[16];
#pragma unroll
    for (int jt = 0; jt < 16; ++jt) {
        acc0[jt] = (f32x4){0.f, 0.f, 0.f, 0.f};
        acc1[jt] = (f32x4){0.f, 0.f, 0.f, 0.f};
    }

    for (int s = 0; s < 8; ++s) {
        short8 a0 = *(const short8*)(Ab + (size_t)(n0w + l15) * F_DIM + s * 32 + g * 8);
        short8 a1 = *(const short8*)(Ab + (size_t)(n0w + 16 + l15) * F_DIM + s * 32 + g * 8);
#pragma unroll
        for (int jt = 0; jt < 16; ++jt) {
            short8 bf = *(const short8*)(Wt + (size_t)(jt * 16 + l15) * F_DIM + s * 32 + g * 8);
            acc0[jt] = __builtin_amdgcn_mfma_f32_16x16x32_bf16(a0, bf, acc0[jt], 0, 0, 0);
            acc1[jt] = __builtin_amdgcn_mfma_f32_16x16x32_bf16(a1, bf, acc1[jt], 0, 0, 0);
        }
    }

#pragma unroll
    for (int jt = 0; jt < 16; ++jt) {
        float bv = ADD_BIAS ? bias[jt * 16 + l15] : 0.f;
#pragma unroll
        for (int q = 0; q < 4; ++q) {
            int r0 = n0w + g * 4 + q;
            C[((size_t)b * N_DIM + r0) * F_DIM + jt * 16 + l15] = acc0[jt][q] + bv;
            int r1 = n0w + 16 + g * 4 + q;
            C[((size_t)b * N_DIM + r1) * F_DIM + jt * 16 + l15] = acc1[jt][q] + bv;
        }
    }
}

// ---------------------------------------------------------------------------
// k_spmm_bf16: x1 = relu(A_hat @ h1 + b1) with PRE-SCALED weights. bf16 out.
// ---------------------------------------------------------------------------
__global__ __launch_bounds__(256) void k_spmm_bf16(const float* __restrict__ X,
                                                   const int* __restrict__ idxb,
                                                   const float* __restrict__ wbs,
                                                   const float* __restrict__ bias,
                                                   unsigned short* __restrict__ Y) {
    const int lid = blockIdx.x;                 // 24576 blocks
    const int slot = lid >> 3;                  // 0..3071
    const int b = (lid & 7) + 8 * (slot >> 7);  // 2 batches/XCD concurrent
    const int rowblk = slot & 127;
    const int w = threadIdx.x >> 6;
    const int l = threadIdx.x & 63;
    const int row = b * N_DIM + rowblk * 4 + w;

    const float* Xb = X + ((size_t)b << 9) * F_DIM;
    const int* id = idxb + row * K_TOP;
    const float* ww = wbs + (size_t)row * 12;

    float4 bv = ((const float4*)bias)[l];
    float4 xv = ((const float4*)(X + (size_t)row * F_DIM))[l];
    const float ws = ww[K_TOP];
    float4 acc;
    acc.x = ws * xv.x + bv.x; acc.y = ws * xv.y + bv.y;
    acc.z = ws * xv.z + bv.z; acc.w = ws * xv.w + bv.w;
#pragma unroll
    for (int i = 0; i < K_TOP; ++i) {
        float wi = ww[i];
        float4 gv = ((const float4*)(Xb + ((size_t)id[i] << 8)))[l];
        acc.x += wi * gv.x; acc.y += wi * gv.y;
        acc.z += wi * gv.z; acc.w += wi * gv.w;
    }
    acc.x = fmaxf(acc.x, 0.f); acc.y = fmaxf(acc.y, 0.f);
    acc.z = fmaxf(acc.z, 0.f); acc.w = fmaxf(acc.w, 0.f);
    uint2 p;
    p.x = (unsigned)f2bf(acc.x) | ((unsigned)f2bf(acc.y) << 16);
    p.y = (unsigned)f2bf(acc.z) | ((unsigned)f2bf(acc.w) << 16);
    ((uint2*)Y)[(size_t)row * (F_DIM / 4) + l] = p;
}

// ---------------------------------------------------------------------------
// k_spmm_trans: x2 = A_hat @ h2 + b2 (pre-scaled weights), out = x2^T + v.
// 16n x 128f tiles: 4 batches/XCD concurrent = 1 MB << L2.
// ---------------------------------------------------------------------------
__global__ __launch_bounds__(256) void k_spmm_trans(const float* __restrict__ X,
                                                    const int* __restrict__ idxb,
                                                    const float* __restrict__ wbs,
                                                    const float* __restrict__ bias,
                                                    const float* __restrict__ v,
                                                    float* __restrict__ out) {
    __shared__ float tile[16][132];
    const int lid = blockIdx.x;                 // 12288 blocks
    const int slot = lid >> 3;                  // 0..1535
    const int b = (lid & 7) + 8 * (slot >> 6);  // 64 tiles/batch
    const int tl = slot & 63;
    const int n0 = (tl & 31) * 16;
    const int f0 = (tl >> 5) * 128;
    const int w = threadIdx.x >> 6;
    const int l = threadIdx.x & 63;

    const float* Xb = X + ((size_t)b << 9) * F_DIM;
    const int rl = l >> 5;                      // row sub-index (0/1)
    const int fq = l & 31;                      // f-quad within half-panel
    float4 bv = ((const float4*)bias)[(f0 >> 2) + fq];

    for (int p2 = 0; p2 < 2; ++p2) {
        const int rloc = p2 * 8 + w * 2 + rl;
        const int row = b * N_DIM + n0 + rloc;
        const int* id = idxb + row * K_TOP;
        const float* ww = wbs + (size_t)row * 12;
        float4 xv = ((const float4*)(X + (size_t)row * F_DIM + f0))[fq];
        const float ws = ww[K_TOP];
        float4 acc;
        acc.x = ws * xv.x + bv.x; acc.y = ws * xv.y + bv.y;
        acc.z = ws * xv.z + bv.z; acc.w = ws * xv.w + bv.w;
#pragma unroll
        for (int i = 0; i < K_TOP; ++i) {
            float wi = ww[i];
            float4 gv = ((const float4*)(Xb + ((size_t)id[i] << 8) + f0))[fq];
            acc.x += wi * gv.x; acc.y += wi * gv.y;
            acc.z += wi * gv.z; acc.w += wi * gv.w;
        }
        tile[rloc][fq * 4 + 0] = acc.x;
        tile[rloc][fq * 4 + 1] = acc.y;
        tile[rloc][fq * 4 + 2] = acc.z;
        tile[rloc][fq * 4 + 3] = acc.w;
    }
    __syncthreads();

    const int i4 = l & 3, fj = l >> 2;
#pragma unroll
    for (int k = 0; k < 2; ++k) {
        const int fl = k * 64 + w * 16 + fj;
        const size_t vo = (size_t)b * F_DIM * N_DIM + (size_t)(f0 + fl) * N_DIM + n0;
        float4 vv = ((const float4*)(v + vo))[i4];
        float4 o;
        o.x = tile[i4 * 4 + 0][fl] + vv.x;
        o.y = tile[i4 * 4 + 1][fl] + vv.y;
        o.z = tile[i4 * 4 + 2][fl] + vv.z;
        o.w = tile[i4 * 4 + 3][fl] + vv.w;
        ((float4*)(out + vo))[i4] = o;
    }
}

// ---------------------------------------------------------------------------
extern "C" void kernel_launch(void* const* d_in, const int* in_sizes, int n_in,
                              void* d_out, int out_size, void* d_ws, size_t ws_size,
                              hipStream_t stream) {
    const float* v   = (const float*)d_in[0];
    const float* g_w = (const float*)d_in[1];
    const float* g_b = (const float*)d_in[2];
    const float* w1  = (const float*)d_in[3];
    const float* b1  = (const float*)d_in[4];
    const float* w2  = (const float*)d_in[5];
    const float* b2  = (const float*)d_in[6];
    float* out = (float*)d_out;

    const size_t S = (size_t)B_DIM * N_DIM * F_DIM;
    float* bufA = (float*)d_ws;                     // h1, then h2 (fp32)
    float* bufB = bufA + S;                         // vt/x1bf in lower half
    float* bc   = bufB + S;
    float* deg  = bc + F_DIM;
    float* wb   = deg + (size_t)B_DIM * N_DIM;      // raw top-10 values
    int*   idxb = (int*)(wb + (size_t)B_DIM * N_DIM * (K_TOP + 1));
    unsigned short* Wt1 = (unsigned short*)(idxb + (size_t)B_DIM * N_DIM * K_TOP);
    unsigned short* W2t = Wt1 + F_DIM * F_DIM;

    unsigned short* vt   = (unsigned short*)bufB;   // lower half of bufB
    unsigned short* x1bf = (unsigned short*)bufB;
    float* wbs = bufB + S / 2;                      // upper half of bufB (free)

    k_combine<<<dim3(2 * F_DIM + 2), 256, 0, stream>>>(g_w, g_b, w1, w2, Wt1, bc, W2t);
    k_to_bf16t<<<dim3(N_DIM / 32, F_DIM / 32, B_DIM), 256, 0, stream>>>(v, vt);
    // affinity + top-10 (m-split waves, 4 waves/SIMD, cross-wave LDS merge)
    k_topk_reg<<<dim3(B_DIM * (N_DIM / 32)), 256, 0, stream>>>(vt, deg, idxb, wb);
    // pre-scale edge weights once
    k_scale<<<dim3(B_DIM * N_DIM / 256), 256, 0, stream>>>(deg, idxb, wb, wbs);
    // h1 = vt @ Wt1^T + bc -> bufA
    k_gemm_mfma<true><<<dim3(N_DIM / 128, B_DIM), 256, 0, stream>>>(vt, Wt1, bc, bufA);
    // x1 = relu(A_hat @ h1 + b1) -> x1bf (bf16)
    k_spmm_bf16<<<dim3(B_DIM * N_DIM / 4), 256, 0, stream>>>(bufA, idxb, wbs, b1, x1bf);
    // h2 = x1bf @ W2t^T -> bufA
    k_gemm_mfma<false><<<dim3(N_DIM / 128, B_DIM), 256, 0, stream>>>(x1bf, W2t, nullptr, bufA);
    // out = (A_hat @ h2 + b2)^T + v
    k_spmm_trans<<<dim3(B_DIM * N_DIM / 16 * 2), 256, 0, stream>>>(bufA, idxb, wbs, b2, v, out);
}